// Round 3
// baseline (784.787 us; speedup 1.0000x reference)
//
#include <hip/hip_runtime.h>
#include <hip/hip_bf16.h>
#include <cstdint>

typedef unsigned short u16;
typedef unsigned int   u32;
typedef __attribute__((ext_vector_type(8))) short short8;   // 8 bf16 (4 VGPRs) MFMA A/B frag
typedef __attribute__((ext_vector_type(4))) float f32x4;    // MFMA C/D frag / float4 load
typedef __attribute__((ext_vector_type(4))) u32  u32x4;     // 16B load/store
typedef __attribute__((ext_vector_type(2))) u32  u32x2;

#define DEV static __device__ __forceinline__

DEV float bf2f(u16 u){ u32 t = ((u32)u) << 16; float f; __builtin_memcpy(&f, &t, 4); return f; }
DEV u16 f2bf(float f){ u32 t; __builtin_memcpy(&t, &f, 4); return (u16)((t + 0x7fffu + ((t >> 16) & 1u)) >> 16); }

// async global->LDS, 16B per lane. dst must be wave-uniform; HW writes dst + lane*16.
DEV void gload_lds16(const void* g, void* l) {
    __builtin_amdgcn_global_load_lds((__attribute__((address_space(1))) void*)(g),
                                     (__attribute__((address_space(3))) void*)(l), 16, 0, 0);
}

// ---------------------------------------------------------------- dtype probe
__global__ __launch_bounds__(256) void detect_mode(const u16* __restrict__ x, int* __restrict__ mode)
{
    __shared__ int red[4];
    const int tid = threadIdx.x;
    int crazy = 0;
    for (int i = tid; i < 1024; i += 256) {
        u16 v = x[2 * i];
        int e = (v >> 7) & 0xFF;
        if (e >= 0x9F || (e > 0 && e <= 0x5F)) crazy++;
    }
    #pragma unroll
    for (int off = 1; off < 64; off <<= 1) crazy += __shfl_xor(crazy, off, 64);
    if ((tid & 63) == 0) red[tid >> 6] = crazy;
    __syncthreads();
    if (tid == 0) *mode = (red[0] + red[1] + red[2] + red[3] > 128) ? 1 : 0;
}

// ---------------------------------------------------------------- canonicalize params to bf16 in ws
// cW layout: Wq|Wk|Wv|Wo (1M each) at ws+33554432.
// cV layout at ws+37748736: [0]norm_w [1024]norm_b [2048]bq [3072]bk [4096]bv
//                           [5120]qn_w [5184]qn_b [5248]kn_w [5312]kn_b   (5376 total)
struct SrcPtrs { const void* p[13]; };

__global__ __launch_bounds__(256) void convert_params(SrcPtrs sp, u16* __restrict__ ws,
                                                      const int* __restrict__ mode)
{
    const bool f = (*mode != 0);
    u16* cW = ws + 33554432;
    u16* cV = ws + 37748736;
    if (blockIdx.x < 16384) {
        const int i = blockIdx.x * 256 + threadIdx.x;          // 0..4194303
        const int t = i >> 20, off = i & 1048575;
        const void* src = (t == 0) ? sp.p[6] : (t == 1) ? sp.p[8] : (t == 2) ? sp.p[10] : sp.p[12];
        cW[i] = f ? f2bf(((const float*)src)[off]) : ((const u16*)src)[off];
    } else {
        const int j = (blockIdx.x - 16384) * 256 + threadIdx.x;
        if (j >= 5376) return;
        const void* src; int off;
        if      (j < 1024) { src = sp.p[0];  off = j; }
        else if (j < 2048) { src = sp.p[1];  off = j - 1024; }
        else if (j < 3072) { src = sp.p[7];  off = j - 2048; }
        else if (j < 4096) { src = sp.p[9];  off = j - 3072; }
        else if (j < 5120) { src = sp.p[11]; off = j - 4096; }
        else { int m = j - 5120; src = sp.p[2 + (m >> 6)]; off = m & 63; }
        cV[j] = f ? f2bf(((const float*)src)[off]) : ((const u16*)src)[off];
    }
}

// ---------------------------------------------------------------- LayerNorm over D=1024 (dual-mode x)
__global__ __launch_bounds__(256) void ln_kernel(const void* __restrict__ x,
                                                 const u16* __restrict__ w,
                                                 const u16* __restrict__ b,
                                                 u16* __restrict__ xn,
                                                 const int* __restrict__ mode)
{
    const int row = blockIdx.x;
    const int tid = threadIdx.x;
    const int wv = tid >> 6, lane = tid & 63;

    float v0, v1, v2, v3;
    if (*mode) {
        f32x4 r = *((const f32x4*)((const float*)x + row * 1024) + tid);
        v0 = r[0]; v1 = r[1]; v2 = r[2]; v3 = r[3];
    } else {
        u32x2 raw = *(const u32x2*)((const u16*)x + row * 1024 + tid * 4);
        v0 = bf2f((u16)(raw.x & 0xffff)); v1 = bf2f((u16)(raw.x >> 16));
        v2 = bf2f((u16)(raw.y & 0xffff)); v3 = bf2f((u16)(raw.y >> 16));
    }
    float s  = v0 + v1 + v2 + v3;
    float sq = v0*v0 + v1*v1 + v2*v2 + v3*v3;
    #pragma unroll
    for (int off = 1; off < 64; off <<= 1) {
        s  += __shfl_xor(s,  off, 64);
        sq += __shfl_xor(sq, off, 64);
    }
    __shared__ float red[8];
    if (lane == 0) { red[wv] = s; red[4 + wv] = sq; }
    __syncthreads();
    float ts = red[0] + red[1] + red[2] + red[3];
    float tq = red[4] + red[5] + red[6] + red[7];
    float mean = ts * (1.0f / 1024.0f);
    float var  = tq * (1.0f / 1024.0f) - mean * mean;
    float rs   = rsqrtf(var + 1e-5f);

    float y0 = (v0 - mean) * rs * bf2f(w[tid*4+0]) + bf2f(b[tid*4+0]);
    float y1 = (v1 - mean) * rs * bf2f(w[tid*4+1]) + bf2f(b[tid*4+1]);
    float y2 = (v2 - mean) * rs * bf2f(w[tid*4+2]) + bf2f(b[tid*4+2]);
    float y3 = (v3 - mean) * rs * bf2f(w[tid*4+3]) + bf2f(b[tid*4+3]);
    u32x2 out;
    out.x = (u32)f2bf(y0) | ((u32)f2bf(y1) << 16);
    out.y = (u32)f2bf(y2) | ((u32)f2bf(y3) << 16);
    *(u32x2*)(xn + row * 1024 + tid * 4) = out;
}

// ---------------------------------------------------------------- m97-class GEMM: C = A[8192][1024] @ W[N][1024]^T
// 128x128 tile, BK=64, global_load_lds(16B) staging, 4 waves each 64x64 (4x4 of 16x16x32).
// epi=1: QKV fused — cols<2048 -> qk[8192][2048] bf16 (+bias); cols>=2048 -> vt[b][h][dh][n] (+bias).
// epi=2: final out — out0 as f32 (if *mode) else bf16, no bias.
__global__ __launch_bounds__(256) void gemm128(const u16* __restrict__ A,
                                               const u16* __restrict__ W,
                                               const u16* __restrict__ bias,
                                               void* __restrict__ out0,
                                               u16* __restrict__ vt,
                                               const int* __restrict__ mode,
                                               int epi, int N)
{
    __shared__ u16 As[128 * 64];
    __shared__ u16 Bs[128 * 64];
    const int tid = threadIdx.x;
    const int m0 = blockIdx.x * 128, n0 = blockIdx.y * 128;
    const int wv = tid >> 6, lane = tid & 63, quad = lane >> 4, l16 = lane & 15;
    const int wm = wv & 1, wn = wv >> 1;

    f32x4 acc[4][4] = {};

    const int srow = tid >> 3, scol = (tid & 7) * 8;           // staging: instr i covers rows [i*32, i*32+32)
    const u16* Ap = A + (size_t)(m0 + srow) * 1024 + scol;
    const u16* Wp = W + (size_t)(n0 + srow) * 1024 + scol;

    for (int k0 = 0; k0 < 1024; k0 += 64) {
        #pragma unroll
        for (int i = 0; i < 4; i++)
            gload_lds16(Ap + k0 + (size_t)i * 32 * 1024, &As[i * 2048 + wv * 512]);
        #pragma unroll
        for (int i = 0; i < 4; i++)
            gload_lds16(Wp + k0 + (size_t)i * 32 * 1024, &Bs[i * 2048 + wv * 512]);
        __syncthreads();
        #pragma unroll
        for (int kh = 0; kh < 64; kh += 32) {
            short8 af[4], bf[4];
            #pragma unroll
            for (int mi = 0; mi < 4; mi++)
                af[mi] = *(const short8*)&As[(wm * 64 + mi * 16 + l16) * 64 + kh + quad * 8];
            #pragma unroll
            for (int ni = 0; ni < 4; ni++)
                bf[ni] = *(const short8*)&Bs[(wn * 64 + ni * 16 + l16) * 64 + kh + quad * 8];
            #pragma unroll
            for (int mi = 0; mi < 4; mi++)
                #pragma unroll
                for (int ni = 0; ni < 4; ni++)
                    acc[mi][ni] = __builtin_amdgcn_mfma_f32_16x16x32_bf16(af[mi], bf[ni], acc[mi][ni], 0, 0, 0);
        }
        __syncthreads();
    }

    if (epi == 1) {
        u16* qk = (u16*)out0;
        const int colbase = n0 + wn * 64;
        if (colbase < 2048) {
            #pragma unroll
            for (int ni = 0; ni < 4; ni++) {
                const int col = colbase + ni * 16 + l16;
                const float bv = bf2f(bias[col]);
                #pragma unroll
                for (int mi = 0; mi < 4; mi++) {
                    const int row0 = m0 + wm * 64 + mi * 16 + quad * 4;
                    #pragma unroll
                    for (int r = 0; r < 4; r++)
                        qk[(size_t)(row0 + r) * 2048 + col] = f2bf(acc[mi][ni][r] + bv);
                }
            }
        } else {
            const int cp0 = colbase - 2048;
            #pragma unroll
            for (int ni = 0; ni < 4; ni++) {
                const int cp = cp0 + ni * 16 + l16;            // 0..1023
                const int h = cp >> 6, dh = cp & 63;
                const float bv = bf2f(bias[2048 + cp]);
                #pragma unroll
                for (int mi = 0; mi < 4; mi++) {
                    const int row0 = m0 + wm * 64 + mi * 16 + quad * 4;
                    const int bb = row0 >> 11, nn = row0 & 2047;
                    u32x2 pk;
                    pk.x = (u32)f2bf(acc[mi][ni][0] + bv) | ((u32)f2bf(acc[mi][ni][1] + bv) << 16);
                    pk.y = (u32)f2bf(acc[mi][ni][2] + bv) | ((u32)f2bf(acc[mi][ni][3] + bv) << 16);
                    *(u32x2*)&vt[(size_t)(((bb * 16 + h) * 64) + dh) * 2048 + nn] = pk;
                }
            }
        }
    } else {
        const bool f32o = (*mode != 0);
        #pragma unroll
        for (int ni = 0; ni < 4; ni++) {
            const int col = n0 + wn * 64 + ni * 16 + l16;
            #pragma unroll
            for (int mi = 0; mi < 4; mi++) {
                const int row0 = m0 + wm * 64 + mi * 16 + quad * 4;
                #pragma unroll
                for (int r = 0; r < 4; r++) {
                    const float val = acc[mi][ni][r];
                    if (f32o) ((float*)out0)[(size_t)(row0 + r) * 1024 + col] = val;
                    else      ((u16*)out0)[(size_t)(row0 + r) * 1024 + col]  = f2bf(val);
                }
            }
        }
    }
}

// ---------------------------------------------------------------- per-head LN over DH=64 (+q scale), in place
// qk layout: [tok][0..1023]=q heads, [tok][1024..2047]=k heads; head-row r: tok=r>>4, h=r&15.
__global__ __launch_bounds__(256) void headln(u16* __restrict__ qk,
                                              const u16* __restrict__ qw, const u16* __restrict__ qb,
                                              const u16* __restrict__ kw, const u16* __restrict__ kb)
{
    const int isK = blockIdx.y;
    const u16* w = isK ? kw : qw;
    const u16* b = isK ? kb : qb;
    const float scale = isK ? 1.0f : 0.125f;
    const int wv = threadIdx.x >> 6, lane = threadIdx.x & 63;
    const int r = blockIdx.x * 4 + wv;
    u16* p = qk + (size_t)(r >> 4) * 2048 + isK * 1024 + (r & 15) * 64;
    float v = bf2f(p[lane]);
    float s = v, sq = v * v;
    #pragma unroll
    for (int off = 1; off < 64; off <<= 1) {
        s  += __shfl_xor(s,  off, 64);
        sq += __shfl_xor(sq, off, 64);
    }
    float mean = s * (1.0f / 64.0f);
    float var  = sq * (1.0f / 64.0f) - mean * mean;
    float rs   = rsqrtf(var + 1e-5f);
    p[lane] = f2bf(((v - mean) * rs * bf2f(w[lane]) + bf2f(b[lane])) * scale);
}

// ---------------------------------------------------------------- flash attention, O^T formulation
// grid (32, 64): x = 64-row Q tile, y = b*16+h. Wave handles 16 Q rows.
// S^T = K*Q^T (C-layout: row=j, col=i=l16) -> stats live at lane i=l16 (no shuffles for rescale).
// P round-trips wave-private LDS: C-layout -> row-major [i][j]; the A-layout read of P
// doubles as the B-layout fragment of P^T. PV^T: D[dh][i] = Vt_rows (A) x P^T (B).
// No __syncthreads in the K-loop (wave-private LDS, in-order DS pipe).
__global__ __launch_bounds__(256) void attn(const u16* __restrict__ qk, const u16* __restrict__ vt,
                                            const int* __restrict__ mask, u16* __restrict__ ctx)
{
    __shared__ float maskf[2048];
    __shared__ u16 Ps[4 * 16 * 40];   // per-wave [i=l16][j 0..31], row stride 40 elems (80B)

    const int bh = blockIdx.y, b = bh >> 4, h = bh & 15;
    const int i0 = blockIdx.x * 64;
    const int tid = threadIdx.x, wv = tid >> 6, lane = tid & 63, quad = lane >> 4, l16 = lane & 15;

    for (int idx = tid; idx < 2048; idx += 256)
        maskf[idx] = mask[b * 2048 + idx] ? 0.0f : -1e9f;

    const u16* qbase = qk + (size_t)(b * 2048) * 2048 + h * 64;
    const u16* kbase = qbase + 1024;
    const u16* vbase = vt + (size_t)(bh * 64) * 2048;   // rows = dh, cols = n

    const int iw = i0 + wv * 16 + l16;
    short8 qf0 = *(const short8*)(qbase + (size_t)iw * 2048 + quad * 8);
    short8 qf1 = *(const short8*)(qbase + (size_t)iw * 2048 + 32 + quad * 8);

    f32x4 O[4] = {{0,0,0,0},{0,0,0,0},{0,0,0,0},{0,0,0,0}};
    float m_run = -1e8f, l_run = 0.0f;
    u16* prow = &Ps[wv * 640 + l16 * 40];

    __syncthreads();   // maskf ready (only barrier in the kernel)

    for (int j0 = 0; j0 < 2048; j0 += 32) {
        f32x4 sfr[2];
        #pragma unroll
        for (int sub = 0; sub < 2; sub++) {
            const int jt = j0 + sub * 16;
            short8 kf0 = *(const short8*)(kbase + (size_t)(jt + l16) * 2048 + quad * 8);
            short8 kf1 = *(const short8*)(kbase + (size_t)(jt + l16) * 2048 + 32 + quad * 8);
            f32x4 sz = {0,0,0,0};
            sz = __builtin_amdgcn_mfma_f32_16x16x32_bf16(kf0, qf0, sz, 0, 0, 0);
            sz = __builtin_amdgcn_mfma_f32_16x16x32_bf16(kf1, qf1, sz, 0, 0, 0);
            sfr[sub] = sz;
        }

        float p[2][4], mt = -1e30f;
        #pragma unroll
        for (int sub = 0; sub < 2; sub++) {
            f32x4 mrow = *(const f32x4*)&maskf[j0 + sub * 16 + quad * 4];
            #pragma unroll
            for (int r = 0; r < 4; r++) {
                float sv = sfr[sub][r] + mrow[r];
                p[sub][r] = sv;
                mt = fmaxf(mt, sv);
            }
        }
        mt = fmaxf(mt, __shfl_xor(mt, 16, 64));
        mt = fmaxf(mt, __shfl_xor(mt, 32, 64));
        float mnew  = fmaxf(m_run, mt);
        float alpha = __expf(m_run - mnew);
        float rsum = 0.0f;
        #pragma unroll
        for (int sub = 0; sub < 2; sub++)
            #pragma unroll
            for (int r = 0; r < 4; r++) {
                float e = __expf(p[sub][r] - mnew);
                p[sub][r] = e;
                rsum += e;
            }
        rsum += __shfl_xor(rsum, 16, 64);
        rsum += __shfl_xor(rsum, 32, 64);
        l_run = l_run * alpha + rsum;
        m_run = mnew;

        #pragma unroll
        for (int dht = 0; dht < 4; dht++)
            #pragma unroll
            for (int r = 0; r < 4; r++) O[dht][r] *= alpha;   // col=i=l16 matches stats lane

        #pragma unroll
        for (int sub = 0; sub < 2; sub++) {
            u32 w0 = (u32)f2bf(p[sub][0]) | ((u32)f2bf(p[sub][1]) << 16);
            u32 w1 = (u32)f2bf(p[sub][2]) | ((u32)f2bf(p[sub][3]) << 16);
            *(u32*)&prow[sub * 16 + quad * 4]     = w0;
            *(u32*)&prow[sub * 16 + quad * 4 + 2] = w1;
        }
        short8 pf = *(const short8*)&prow[quad * 8];

        #pragma unroll
        for (int dht = 0; dht < 4; dht++) {
            short8 vf = *(const short8*)(vbase + (size_t)(dht * 16 + l16) * 2048 + j0 + quad * 8);
            O[dht] = __builtin_amdgcn_mfma_f32_16x16x32_bf16(vf, pf, O[dht], 0, 0, 0);
        }
    }

    const float inv = l_run > 0.0f ? 1.0f / l_run : 0.0f;     // valid for i=l16
    u16* cb = ctx + (size_t)(b * 2048 + iw) * 1024 + h * 64;
    #pragma unroll
    for (int dht = 0; dht < 4; dht++) {
        u32x2 pk;
        pk.x = (u32)f2bf(O[dht][0] * inv) | ((u32)f2bf(O[dht][1] * inv) << 16);
        pk.y = (u32)f2bf(O[dht][2] * inv) | ((u32)f2bf(O[dht][3] * inv) << 16);
        *(u32x2*)(cb + dht * 16 + quad * 4) = pk;
    }
}

// ----------------------------------------------------------------
extern "C" void kernel_launch(void* const* d_in, const int* in_sizes, int n_in,
                              void* d_out, int out_size, void* d_ws, size_t ws_size,
                              hipStream_t stream)
{
    const int* mask = (const int*)d_in[1];

    u16* ws = (u16*)d_ws;
    u16* xn  = ws;                      // [0, 8388608)
    u16* qkb = ws + 8388608;            // [8388608, 25165824)  [8192][2048]
    u16* vtb = ws + 25165824;           // [25165824, 33554432) [4][16][64][2048]
    u16* ctx = xn;                      // xn dead after QKV GEMM; reuse
    u16* cW  = ws + 33554432;           // Wq|Wk|Wv|Wo
    u16* cV  = ws + 37748736;           // vectors (5376)
    int* mode = (int*)(ws + 37754176);

    detect_mode<<<dim3(1), dim3(256), 0, stream>>>((const u16*)d_in[0], mode);

    SrcPtrs sp;
    for (int i = 0; i < 13; i++) sp.p[i] = d_in[i + 2];
    convert_params<<<dim3(16405), dim3(256), 0, stream>>>(sp, ws, mode);

    ln_kernel<<<dim3(8192), dim3(256), 0, stream>>>(d_in[0], cV + 0, cV + 1024, xn, mode);

    // fused QKV: N=3072, stacked W = cW (Wq|Wk|Wv), stacked bias = cV+2048 (bq|bk|bv)
    gemm128<<<dim3(64, 24), dim3(256), 0, stream>>>(xn, cW, cV + 2048, qkb, vtb, mode, 1, 3072);

    headln<<<dim3(32768, 2), dim3(256), 0, stream>>>(qkb, cV + 5120, cV + 5184, cV + 5248, cV + 5312);

    attn<<<dim3(32, 64), dim3(256), 0, stream>>>(qkb, vtb, mask, ctx);

    gemm128<<<dim3(64, 8), dim3(256), 0, stream>>>(ctx, cW + 3145728, nullptr, d_out, nullptr, mode, 2, 1024);
}

// Round 4
// 530.529 us; speedup vs baseline: 1.4793x; 1.4793x over previous
//
#include <hip/hip_runtime.h>
#include <hip/hip_bf16.h>
#include <cstdint>

typedef unsigned short u16;
typedef unsigned int   u32;
typedef __attribute__((ext_vector_type(8))) short short8;   // 8 bf16 (4 VGPRs) MFMA A/B frag
typedef __attribute__((ext_vector_type(4))) float f32x4;    // MFMA C/D frag / float4 load
typedef __attribute__((ext_vector_type(4))) u32  u32x4;     // 16B load/store
typedef __attribute__((ext_vector_type(2))) u32  u32x2;

#define DEV static __device__ __forceinline__

DEV float bf2f(u16 u){ u32 t = ((u32)u) << 16; float f; __builtin_memcpy(&f, &t, 4); return f; }
DEV u16 f2bf(float f){ u32 t; __builtin_memcpy(&t, &f, 4); return (u16)((t + 0x7fffu + ((t >> 16) & 1u)) >> 16); }
// truncating pack (round-toward-zero; used only for P in [0,1])
DEV u32 pack_trunc(float a, float b){
    u32 ta, tb; __builtin_memcpy(&ta, &a, 4); __builtin_memcpy(&tb, &b, 4);
    return (ta >> 16) | (tb & 0xFFFF0000u);
}

// async global->LDS, 16B per lane. LDS dst must be wave-uniform; HW writes dst + lane*16.
DEV void gload_lds16(const void* g, void* l) {
    __builtin_amdgcn_global_load_lds((__attribute__((address_space(1))) void*)(g),
                                     (__attribute__((address_space(3))) void*)(l), 16, 0, 0);
}

// ---------------------------------------------------------------- dtype probe
__global__ __launch_bounds__(256) void detect_mode(const u16* __restrict__ x, int* __restrict__ mode)
{
    __shared__ int red[4];
    const int tid = threadIdx.x;
    int crazy = 0;
    for (int i = tid; i < 1024; i += 256) {
        u16 v = x[2 * i];
        int e = (v >> 7) & 0xFF;
        if (e >= 0x9F || (e > 0 && e <= 0x5F)) crazy++;
    }
    #pragma unroll
    for (int off = 1; off < 64; off <<= 1) crazy += __shfl_xor(crazy, off, 64);
    if ((tid & 63) == 0) red[tid >> 6] = crazy;
    __syncthreads();
    if (tid == 0) *mode = (red[0] + red[1] + red[2] + red[3] > 128) ? 1 : 0;
}

// ---------------------------------------------------------------- canonicalize params to bf16 in ws
// cW layout: Wq|Wk|Wv|Wo (1M each) at ws+33554432.
// cV layout at ws+37748736: [0]norm_w [1024]norm_b [2048]bq [3072]bk [4096]bv
//                           [5120]qn_w [5184]qn_b [5248]kn_w [5312]kn_b   (5376 total)
struct SrcPtrs { const void* p[13]; };

__global__ __launch_bounds__(256) void convert_params(SrcPtrs sp, u16* __restrict__ ws,
                                                      const int* __restrict__ mode)
{
    const bool f = (*mode != 0);
    u16* cW = ws + 33554432;
    u16* cV = ws + 37748736;
    if (blockIdx.x < 16384) {
        const int i = blockIdx.x * 256 + threadIdx.x;          // 0..4194303
        const int t = i >> 20, off = i & 1048575;
        const void* src = (t == 0) ? sp.p[6] : (t == 1) ? sp.p[8] : (t == 2) ? sp.p[10] : sp.p[12];
        cW[i] = f ? f2bf(((const float*)src)[off]) : ((const u16*)src)[off];
    } else {
        const int j = (blockIdx.x - 16384) * 256 + threadIdx.x;
        if (j >= 5376) return;
        const void* src; int off;
        if      (j < 1024) { src = sp.p[0];  off = j; }
        else if (j < 2048) { src = sp.p[1];  off = j - 1024; }
        else if (j < 3072) { src = sp.p[7];  off = j - 2048; }
        else if (j < 4096) { src = sp.p[9];  off = j - 3072; }
        else if (j < 5120) { src = sp.p[11]; off = j - 4096; }
        else { int m = j - 5120; src = sp.p[2 + (m >> 6)]; off = m & 63; }
        cV[j] = f ? f2bf(((const float*)src)[off]) : ((const u16*)src)[off];
    }
}

// ---------------------------------------------------------------- LayerNorm over D=1024 (dual-mode x)
__global__ __launch_bounds__(256) void ln_kernel(const void* __restrict__ x,
                                                 const u16* __restrict__ w,
                                                 const u16* __restrict__ b,
                                                 u16* __restrict__ xn,
                                                 const int* __restrict__ mode)
{
    const int row = blockIdx.x;
    const int tid = threadIdx.x;
    const int wv = tid >> 6, lane = tid & 63;

    float v0, v1, v2, v3;
    if (*mode) {
        f32x4 r = *((const f32x4*)((const float*)x + row * 1024) + tid);
        v0 = r[0]; v1 = r[1]; v2 = r[2]; v3 = r[3];
    } else {
        u32x2 raw = *(const u32x2*)((const u16*)x + row * 1024 + tid * 4);
        v0 = bf2f((u16)(raw.x & 0xffff)); v1 = bf2f((u16)(raw.x >> 16));
        v2 = bf2f((u16)(raw.y & 0xffff)); v3 = bf2f((u16)(raw.y >> 16));
    }
    float s  = v0 + v1 + v2 + v3;
    float sq = v0*v0 + v1*v1 + v2*v2 + v3*v3;
    #pragma unroll
    for (int off = 1; off < 64; off <<= 1) {
        s  += __shfl_xor(s,  off, 64);
        sq += __shfl_xor(sq, off, 64);
    }
    __shared__ float red[8];
    if (lane == 0) { red[wv] = s; red[4 + wv] = sq; }
    __syncthreads();
    float ts = red[0] + red[1] + red[2] + red[3];
    float tq = red[4] + red[5] + red[6] + red[7];
    float mean = ts * (1.0f / 1024.0f);
    float var  = tq * (1.0f / 1024.0f) - mean * mean;
    float rs   = rsqrtf(var + 1e-5f);

    float y0 = (v0 - mean) * rs * bf2f(w[tid*4+0]) + bf2f(b[tid*4+0]);
    float y1 = (v1 - mean) * rs * bf2f(w[tid*4+1]) + bf2f(b[tid*4+1]);
    float y2 = (v2 - mean) * rs * bf2f(w[tid*4+2]) + bf2f(b[tid*4+2]);
    float y3 = (v3 - mean) * rs * bf2f(w[tid*4+3]) + bf2f(b[tid*4+3]);
    u32x2 out;
    out.x = (u32)f2bf(y0) | ((u32)f2bf(y1) << 16);
    out.y = (u32)f2bf(y2) | ((u32)f2bf(y3) << 16);
    *(u32x2*)(xn + row * 1024 + tid * 4) = out;
}

// ---------------------------------------------------------------- m97-class GEMM: C = A[8192][1024] @ W[N][1024]^T
// 128x128 tile, BK=64, global_load_lds(16B) staging, 4 waves each 64x64 (4x4 of 16x16x32).
// epi=1: QKV fused — cols<2048 -> qk[8192][2048] bf16 (+bias); cols>=2048 -> vt[b][h][dh][n] (+bias).
// epi=2: final out — out0 as f32 (if *mode) else bf16, no bias.
__global__ __launch_bounds__(256) void gemm128(const u16* __restrict__ A,
                                               const u16* __restrict__ W,
                                               const u16* __restrict__ bias,
                                               void* __restrict__ out0,
                                               u16* __restrict__ vt,
                                               const int* __restrict__ mode,
                                               int epi, int N)
{
    __shared__ u16 As[128 * 64];
    __shared__ u16 Bs[128 * 64];
    const int tid = threadIdx.x;
    const int m0 = blockIdx.x * 128, n0 = blockIdx.y * 128;
    const int wv = tid >> 6, lane = tid & 63, quad = lane >> 4, l16 = lane & 15;
    const int wm = wv & 1, wn = wv >> 1;

    f32x4 acc[4][4] = {};

    const int srow = tid >> 3, scol = (tid & 7) * 8;           // staging: instr i covers rows [i*32, i*32+32)
    const u16* Ap = A + (size_t)(m0 + srow) * 1024 + scol;
    const u16* Wp = W + (size_t)(n0 + srow) * 1024 + scol;

    for (int k0 = 0; k0 < 1024; k0 += 64) {
        #pragma unroll
        for (int i = 0; i < 4; i++)
            gload_lds16(Ap + k0 + (size_t)i * 32 * 1024, &As[i * 2048 + wv * 512]);
        #pragma unroll
        for (int i = 0; i < 4; i++)
            gload_lds16(Wp + k0 + (size_t)i * 32 * 1024, &Bs[i * 2048 + wv * 512]);
        __syncthreads();
        #pragma unroll
        for (int kh = 0; kh < 64; kh += 32) {
            short8 af[4], bf[4];
            #pragma unroll
            for (int mi = 0; mi < 4; mi++)
                af[mi] = *(const short8*)&As[(wm * 64 + mi * 16 + l16) * 64 + kh + quad * 8];
            #pragma unroll
            for (int ni = 0; ni < 4; ni++)
                bf[ni] = *(const short8*)&Bs[(wn * 64 + ni * 16 + l16) * 64 + kh + quad * 8];
            #pragma unroll
            for (int mi = 0; mi < 4; mi++)
                #pragma unroll
                for (int ni = 0; ni < 4; ni++)
                    acc[mi][ni] = __builtin_amdgcn_mfma_f32_16x16x32_bf16(af[mi], bf[ni], acc[mi][ni], 0, 0, 0);
        }
        __syncthreads();
    }

    if (epi == 1) {
        u16* qk = (u16*)out0;
        const int colbase = n0 + wn * 64;
        if (colbase < 2048) {
            #pragma unroll
            for (int ni = 0; ni < 4; ni++) {
                const int col = colbase + ni * 16 + l16;
                const float bv = bf2f(bias[col]);
                #pragma unroll
                for (int mi = 0; mi < 4; mi++) {
                    const int row0 = m0 + wm * 64 + mi * 16 + quad * 4;
                    #pragma unroll
                    for (int r = 0; r < 4; r++)
                        qk[(size_t)(row0 + r) * 2048 + col] = f2bf(acc[mi][ni][r] + bv);
                }
            }
        } else {
            const int cp0 = colbase - 2048;
            #pragma unroll
            for (int ni = 0; ni < 4; ni++) {
                const int cp = cp0 + ni * 16 + l16;            // 0..1023
                const int h = cp >> 6, dh = cp & 63;
                const float bv = bf2f(bias[2048 + cp]);
                #pragma unroll
                for (int mi = 0; mi < 4; mi++) {
                    const int row0 = m0 + wm * 64 + mi * 16 + quad * 4;
                    const int bb = row0 >> 11, nn = row0 & 2047;
                    u32x2 pk;
                    pk.x = (u32)f2bf(acc[mi][ni][0] + bv) | ((u32)f2bf(acc[mi][ni][1] + bv) << 16);
                    pk.y = (u32)f2bf(acc[mi][ni][2] + bv) | ((u32)f2bf(acc[mi][ni][3] + bv) << 16);
                    *(u32x2*)&vt[(size_t)(((bb * 16 + h) * 64) + dh) * 2048 + nn] = pk;
                }
            }
        }
    } else {
        const bool f32o = (*mode != 0);
        #pragma unroll
        for (int ni = 0; ni < 4; ni++) {
            const int col = n0 + wn * 64 + ni * 16 + l16;
            #pragma unroll
            for (int mi = 0; mi < 4; mi++) {
                const int row0 = m0 + wm * 64 + mi * 16 + quad * 4;
                #pragma unroll
                for (int r = 0; r < 4; r++) {
                    const float val = acc[mi][ni][r];
                    if (f32o) ((float*)out0)[(size_t)(row0 + r) * 1024 + col] = val;
                    else      ((u16*)out0)[(size_t)(row0 + r) * 1024 + col]  = f2bf(val);
                }
            }
        }
    }
}

// ---------------------------------------------------------------- per-head LN over DH=64, in place
// q scale folds DH^-0.5 AND log2(e) (attn softmax runs in base-2 domain).
__global__ __launch_bounds__(256) void headln(u16* __restrict__ qk,
                                              const u16* __restrict__ qw, const u16* __restrict__ qb,
                                              const u16* __restrict__ kw, const u16* __restrict__ kb)
{
    const int isK = blockIdx.y;
    const u16* w = isK ? kw : qw;
    const u16* b = isK ? kb : qb;
    const float scale = isK ? 1.0f : 0.18033688011112042f;   // 0.125 * log2(e)
    const int wv = threadIdx.x >> 6, lane = threadIdx.x & 63;
    const int r = blockIdx.x * 4 + wv;
    u16* p = qk + (size_t)(r >> 4) * 2048 + isK * 1024 + (r & 15) * 64;
    float v = bf2f(p[lane]);
    float s = v, sq = v * v;
    #pragma unroll
    for (int off = 1; off < 64; off <<= 1) {
        s  += __shfl_xor(s,  off, 64);
        sq += __shfl_xor(sq, off, 64);
    }
    float mean = s * (1.0f / 64.0f);
    float var  = sq * (1.0f / 64.0f) - mean * mean;
    float rs   = rsqrtf(var + 1e-5f);
    p[lane] = f2bf(((v - mean) * rs * bf2f(w[lane]) + bf2f(b[lane])) * scale);
}

// ---------------------------------------------------------------- flash attention, O^T formulation, LDS-staged K/V
// grid (32, 64): x = 64-row Q tile, y = b*16+h. Wave handles 16 Q rows; all 4 waves share
// the K/V tiles (64 keys/iter) staged once per block via async global_load_lds (16B width).
// S^T = K*Q^T with C initialized from the mask row (saves the add). Softmax in base-2
// (q pre-scaled by log2e). P round-trips wave-private LDS into the B-frag of P^T.
// PV^T: O[dh][i] = Vt (A) x P^T (B); stats live at lane i=l16 -> no alpha shuffles.
__global__ __launch_bounds__(256) void attn(const u16* __restrict__ qk, const u16* __restrict__ vt,
                                            const int* __restrict__ mask, u16* __restrict__ ctx)
{
    __shared__ __align__(16) float maskf[2048];     // 8 KB
    __shared__ __align__(16) u16 Ks[64 * 64];       // 8 KB  [j][dh], stride 64
    __shared__ __align__(16) u16 Vs[64 * 64];       // 8 KB  [dh][j], stride 64
    __shared__ __align__(16) u16 Ps[4 * 16 * 72];   // 9 KB  per-wave [i][j0..63], stride 72 (144B, 16B-mult)

    const int bh = blockIdx.y, b = bh >> 4, h = bh & 15;
    const int i0 = blockIdx.x * 64;
    const int tid = threadIdx.x, wv = tid >> 6, lane = tid & 63, quad = lane >> 4, l16 = lane & 15;

    for (int idx = tid; idx < 2048; idx += 256)
        maskf[idx] = mask[b * 2048 + idx] ? 0.0f : -1e9f;

    const u16* qbase = qk + (size_t)(b * 2048) * 2048 + h * 64;
    const u16* kbase = qbase + 1024;
    const u16* vbase = vt + (size_t)(bh * 64) * 2048;   // rows = dh, cols = n

    const int iw = i0 + wv * 16 + l16;
    short8 qf0 = *(const short8*)(qbase + (size_t)iw * 2048 + quad * 8);
    short8 qf1 = *(const short8*)(qbase + (size_t)iw * 2048 + 32 + quad * 8);

    f32x4 O[4] = {{0,0,0,0},{0,0,0,0},{0,0,0,0},{0,0,0,0}};
    float m_run = -1e8f, l_run = 0.0f;
    u16* prow = &Ps[(wv * 16 + l16) * 72];

    const int sj = lane >> 3;            // staging: row within 8-row instr
    const int sc = (lane & 7) * 8;       // 16B chunk within 128B row

    for (int j0 = 0; j0 < 2048; j0 += 64) {
        // stage K tile [j][dh] and V^T tile [dh][j]; wave wv covers rows wv*16..wv*16+15
        #pragma unroll
        for (int i = 0; i < 2; i++) {
            const int r = wv * 16 + i * 8;
            gload_lds16(kbase + (size_t)(j0 + r + sj) * 2048 + sc, &Ks[r * 64]);
            gload_lds16(vbase + (size_t)(r + sj) * 2048 + j0 + sc, &Vs[r * 64]);
        }
        __syncthreads();   // vmcnt drain + barrier: tiles (and, on iter 0, maskf) ready

        // S^T: 4 j-subtiles of 16, C initialized with mask row
        f32x4 sfr[4];
        #pragma unroll
        for (int sub = 0; sub < 4; sub++) {
            short8 kf0 = *(const short8*)&Ks[(sub * 16 + l16) * 64 + quad * 8];
            short8 kf1 = *(const short8*)&Ks[(sub * 16 + l16) * 64 + 32 + quad * 8];
            f32x4 sz = *(const f32x4*)&maskf[j0 + sub * 16 + quad * 4];
            sz = __builtin_amdgcn_mfma_f32_16x16x32_bf16(kf0, qf0, sz, 0, 0, 0);
            sz = __builtin_amdgcn_mfma_f32_16x16x32_bf16(kf1, qf1, sz, 0, 0, 0);
            sfr[sub] = sz;
        }

        // online softmax, base-2 domain; stats replicated across quads at lane i=l16
        float mt = -1e30f;
        #pragma unroll
        for (int sub = 0; sub < 4; sub++)
            #pragma unroll
            for (int r = 0; r < 4; r++) mt = fmaxf(mt, sfr[sub][r]);
        mt = fmaxf(mt, __shfl_xor(mt, 16, 64));
        mt = fmaxf(mt, __shfl_xor(mt, 32, 64));
        float mnew  = fmaxf(m_run, mt);
        float alpha = exp2f(m_run - mnew);
        float rsum = 0.0f;
        #pragma unroll
        for (int sub = 0; sub < 4; sub++)
            #pragma unroll
            for (int r = 0; r < 4; r++) {
                float e = exp2f(sfr[sub][r] - mnew);
                sfr[sub][r] = e;
                rsum += e;
            }
        rsum += __shfl_xor(rsum, 16, 64);
        rsum += __shfl_xor(rsum, 32, 64);
        l_run = l_run * alpha + rsum;
        m_run = mnew;

        #pragma unroll
        for (int dht = 0; dht < 4; dht++)
            #pragma unroll
            for (int r = 0; r < 4; r++) O[dht][r] *= alpha;

        // P -> wave-private LDS rows [i=l16][j]; trunc-pack (P in [0,1])
        #pragma unroll
        for (int sub = 0; sub < 4; sub++) {
            u32x2 pk;
            pk.x = pack_trunc(sfr[sub][0], sfr[sub][1]);
            pk.y = pack_trunc(sfr[sub][2], sfr[sub][3]);
            *(u32x2*)&prow[sub * 16 + quad * 4] = pk;
        }
        short8 pf0 = *(const short8*)&prow[quad * 8];
        short8 pf1 = *(const short8*)&prow[32 + quad * 8];

        // PV^T: O[dh][i] += Vt x P^T over 64 keys
        #pragma unroll
        for (int dht = 0; dht < 4; dht++) {
            short8 vf0 = *(const short8*)&Vs[(dht * 16 + l16) * 64 + quad * 8];
            short8 vf1 = *(const short8*)&Vs[(dht * 16 + l16) * 64 + 32 + quad * 8];
            O[dht] = __builtin_amdgcn_mfma_f32_16x16x32_bf16(vf0, pf0, O[dht], 0, 0, 0);
            O[dht] = __builtin_amdgcn_mfma_f32_16x16x32_bf16(vf1, pf1, O[dht], 0, 0, 0);
        }
        __syncthreads();   // all waves done reading before next stage overwrites
    }

    const float inv = l_run > 0.0f ? 1.0f / l_run : 0.0f;     // valid for i=l16
    u16* cb = ctx + (size_t)(b * 2048 + iw) * 1024 + h * 64;
    #pragma unroll
    for (int dht = 0; dht < 4; dht++) {
        u32x2 pk;
        pk.x = (u32)f2bf(O[dht][0] * inv) | ((u32)f2bf(O[dht][1] * inv) << 16);
        pk.y = (u32)f2bf(O[dht][2] * inv) | ((u32)f2bf(O[dht][3] * inv) << 16);
        *(u32x2*)(cb + dht * 16 + quad * 4) = pk;
    }
}

// ----------------------------------------------------------------
extern "C" void kernel_launch(void* const* d_in, const int* in_sizes, int n_in,
                              void* d_out, int out_size, void* d_ws, size_t ws_size,
                              hipStream_t stream)
{
    const int* mask = (const int*)d_in[1];

    u16* ws = (u16*)d_ws;
    u16* xn  = ws;                      // [0, 8388608)
    u16* qkb = ws + 8388608;            // [8388608, 25165824)  [8192][2048]
    u16* vtb = ws + 25165824;           // [25165824, 33554432) [4][16][64][2048]
    u16* ctx = xn;                      // xn dead after QKV GEMM; reuse
    u16* cW  = ws + 33554432;           // Wq|Wk|Wv|Wo
    u16* cV  = ws + 37748736;           // vectors (5376)
    int* mode = (int*)(ws + 37754176);

    detect_mode<<<dim3(1), dim3(256), 0, stream>>>((const u16*)d_in[0], mode);

    SrcPtrs sp;
    for (int i = 0; i < 13; i++) sp.p[i] = d_in[i + 2];
    convert_params<<<dim3(16405), dim3(256), 0, stream>>>(sp, ws, mode);

    ln_kernel<<<dim3(8192), dim3(256), 0, stream>>>(d_in[0], cV + 0, cV + 1024, xn, mode);

    // fused QKV: N=3072, stacked W = cW (Wq|Wk|Wv), stacked bias = cV+2048 (bq|bk|bv)
    gemm128<<<dim3(64, 24), dim3(256), 0, stream>>>(xn, cW, cV + 2048, qkb, vtb, mode, 1, 3072);

    headln<<<dim3(32768, 2), dim3(256), 0, stream>>>(qkb, cV + 5120, cV + 5184, cV + 5248, cV + 5312);

    attn<<<dim3(32, 64), dim3(256), 0, stream>>>(qkb, vtb, mask, ctx);

    gemm128<<<dim3(64, 8), dim3(256), 0, stream>>>(ctx, cW + 3145728, nullptr, d_out, nullptr, mode, 2, 1024);
}

// Round 5
// 484.185 us; speedup vs baseline: 1.6208x; 1.0957x over previous
//
#include <hip/hip_runtime.h>
#include <hip/hip_bf16.h>
#include <cstdint>

typedef unsigned short u16;
typedef unsigned int   u32;
typedef __attribute__((ext_vector_type(8))) short short8;   // 8 bf16 (4 VGPRs) MFMA A/B frag
typedef __attribute__((ext_vector_type(4))) float f32x4;    // MFMA C/D frag / float4 load
typedef __attribute__((ext_vector_type(4))) u32  u32x4;     // 16B load/store
typedef __attribute__((ext_vector_type(2))) u32  u32x2;

#define DEV static __device__ __forceinline__

DEV float bf2f(u16 u){ u32 t = ((u32)u) << 16; float f; __builtin_memcpy(&f, &t, 4); return f; }
DEV u16 f2bf(float f){ u32 t; __builtin_memcpy(&t, &f, 4); return (u16)((t + 0x7fffu + ((t >> 16) & 1u)) >> 16); }
// truncating pack (round-toward-zero; used only for P in [0,1))
DEV u32 pack_trunc(float a, float b){
    u32 ta, tb; __builtin_memcpy(&ta, &a, 4); __builtin_memcpy(&tb, &b, 4);
    return (ta >> 16) | (tb & 0xFFFF0000u);
}

// async global->LDS, 16B per lane. LDS dst must be wave-uniform; HW writes dst + lane*16.
DEV void gload_lds16(const void* g, void* l) {
    __builtin_amdgcn_global_load_lds((__attribute__((address_space(1))) void*)(g),
                                     (__attribute__((address_space(3))) void*)(l), 16, 0, 0);
}

// ---------------------------------------------------------------- dtype probe
__global__ __launch_bounds__(256) void detect_mode(const u16* __restrict__ x, int* __restrict__ mode)
{
    __shared__ int red[4];
    const int tid = threadIdx.x;
    int crazy = 0;
    for (int i = tid; i < 1024; i += 256) {
        u16 v = x[2 * i];
        int e = (v >> 7) & 0xFF;
        if (e >= 0x9F || (e > 0 && e <= 0x5F)) crazy++;
    }
    #pragma unroll
    for (int off = 1; off < 64; off <<= 1) crazy += __shfl_xor(crazy, off, 64);
    if ((tid & 63) == 0) red[tid >> 6] = crazy;
    __syncthreads();
    if (tid == 0) *mode = (red[0] + red[1] + red[2] + red[3] > 128) ? 1 : 0;
}

// ---------------------------------------------------------------- canonicalize params to bf16 in ws
// cW layout: Wq|Wk|Wv|Wo (1M each) at ws+33554432.
// cV layout at ws+37748736: [0]norm_w [1024]norm_b [2048]bq [3072]bk [4096]bv
//                           [5120]qn_w [5184]qn_b [5248]kn_w [5312]kn_b   (5376 total)
struct SrcPtrs { const void* p[13]; };

__global__ __launch_bounds__(256) void convert_params(SrcPtrs sp, u16* __restrict__ ws,
                                                      const int* __restrict__ mode)
{
    const bool f = (*mode != 0);
    u16* cW = ws + 33554432;
    u16* cV = ws + 37748736;
    if (blockIdx.x < 16384) {
        const int i = blockIdx.x * 256 + threadIdx.x;          // 0..4194303
        const int t = i >> 20, off = i & 1048575;
        const void* src = (t == 0) ? sp.p[6] : (t == 1) ? sp.p[8] : (t == 2) ? sp.p[10] : sp.p[12];
        cW[i] = f ? f2bf(((const float*)src)[off]) : ((const u16*)src)[off];
    } else {
        const int j = (blockIdx.x - 16384) * 256 + threadIdx.x;
        if (j >= 5376) return;
        const void* src; int off;
        if      (j < 1024) { src = sp.p[0];  off = j; }
        else if (j < 2048) { src = sp.p[1];  off = j - 1024; }
        else if (j < 3072) { src = sp.p[7];  off = j - 2048; }
        else if (j < 4096) { src = sp.p[9];  off = j - 3072; }
        else if (j < 5120) { src = sp.p[11]; off = j - 4096; }
        else { int m = j - 5120; src = sp.p[2 + (m >> 6)]; off = m & 63; }
        cV[j] = f ? f2bf(((const float*)src)[off]) : ((const u16*)src)[off];
    }
}

// ---------------------------------------------------------------- LayerNorm over D=1024 (dual-mode x)
__global__ __launch_bounds__(256) void ln_kernel(const void* __restrict__ x,
                                                 const u16* __restrict__ w,
                                                 const u16* __restrict__ b,
                                                 u16* __restrict__ xn,
                                                 const int* __restrict__ mode)
{
    const int row = blockIdx.x;
    const int tid = threadIdx.x;
    const int wv = tid >> 6, lane = tid & 63;

    float v0, v1, v2, v3;
    if (*mode) {
        f32x4 r = *((const f32x4*)((const float*)x + row * 1024) + tid);
        v0 = r[0]; v1 = r[1]; v2 = r[2]; v3 = r[3];
    } else {
        u32x2 raw = *(const u32x2*)((const u16*)x + row * 1024 + tid * 4);
        v0 = bf2f((u16)(raw.x & 0xffff)); v1 = bf2f((u16)(raw.x >> 16));
        v2 = bf2f((u16)(raw.y & 0xffff)); v3 = bf2f((u16)(raw.y >> 16));
    }
    float s  = v0 + v1 + v2 + v3;
    float sq = v0*v0 + v1*v1 + v2*v2 + v3*v3;
    #pragma unroll
    for (int off = 1; off < 64; off <<= 1) {
        s  += __shfl_xor(s,  off, 64);
        sq += __shfl_xor(sq, off, 64);
    }
    __shared__ float red[8];
    if (lane == 0) { red[wv] = s; red[4 + wv] = sq; }
    __syncthreads();
    float ts = red[0] + red[1] + red[2] + red[3];
    float tq = red[4] + red[5] + red[6] + red[7];
    float mean = ts * (1.0f / 1024.0f);
    float var  = tq * (1.0f / 1024.0f) - mean * mean;
    float rs   = rsqrtf(var + 1e-5f);

    float y0 = (v0 - mean) * rs * bf2f(w[tid*4+0]) + bf2f(b[tid*4+0]);
    float y1 = (v1 - mean) * rs * bf2f(w[tid*4+1]) + bf2f(b[tid*4+1]);
    float y2 = (v2 - mean) * rs * bf2f(w[tid*4+2]) + bf2f(b[tid*4+2]);
    float y3 = (v3 - mean) * rs * bf2f(w[tid*4+3]) + bf2f(b[tid*4+3]);
    u32x2 out;
    out.x = (u32)f2bf(y0) | ((u32)f2bf(y1) << 16);
    out.y = (u32)f2bf(y2) | ((u32)f2bf(y3) << 16);
    *(u32x2*)(xn + row * 1024 + tid * 4) = out;
}

// ---------------------------------------------------------------- m97-class GEMM: C = A[8192][1024] @ W[N][1024]^T
// 128x128 tile, BK=64, global_load_lds(16B) staging, 4 waves each 64x64 (4x4 of 16x16x32).
// epi=1: QKV fused — cols<2048 -> qk[8192][2048] bf16 (+bias); cols>=2048 -> vt[b][h][dh][n] (+bias).
// epi=2: final out — out0 as f32 (if *mode) else bf16, no bias.
__global__ __launch_bounds__(256) void gemm128(const u16* __restrict__ A,
                                               const u16* __restrict__ W,
                                               const u16* __restrict__ bias,
                                               void* __restrict__ out0,
                                               u16* __restrict__ vt,
                                               const int* __restrict__ mode,
                                               int epi, int N)
{
    __shared__ u16 As[128 * 64];
    __shared__ u16 Bs[128 * 64];
    const int tid = threadIdx.x;
    const int m0 = blockIdx.x * 128, n0 = blockIdx.y * 128;
    const int wv = tid >> 6, lane = tid & 63, quad = lane >> 4, l16 = lane & 15;
    const int wm = wv & 1, wn = wv >> 1;

    f32x4 acc[4][4] = {};

    const int srow = tid >> 3, scol = (tid & 7) * 8;           // staging: instr i covers rows [i*32, i*32+32)
    const u16* Ap = A + (size_t)(m0 + srow) * 1024 + scol;
    const u16* Wp = W + (size_t)(n0 + srow) * 1024 + scol;

    for (int k0 = 0; k0 < 1024; k0 += 64) {
        #pragma unroll
        for (int i = 0; i < 4; i++)
            gload_lds16(Ap + k0 + (size_t)i * 32 * 1024, &As[i * 2048 + wv * 512]);
        #pragma unroll
        for (int i = 0; i < 4; i++)
            gload_lds16(Wp + k0 + (size_t)i * 32 * 1024, &Bs[i * 2048 + wv * 512]);
        __syncthreads();
        #pragma unroll
        for (int kh = 0; kh < 64; kh += 32) {
            short8 af[4], bf[4];
            #pragma unroll
            for (int mi = 0; mi < 4; mi++)
                af[mi] = *(const short8*)&As[(wm * 64 + mi * 16 + l16) * 64 + kh + quad * 8];
            #pragma unroll
            for (int ni = 0; ni < 4; ni++)
                bf[ni] = *(const short8*)&Bs[(wn * 64 + ni * 16 + l16) * 64 + kh + quad * 8];
            #pragma unroll
            for (int mi = 0; mi < 4; mi++)
                #pragma unroll
                for (int ni = 0; ni < 4; ni++)
                    acc[mi][ni] = __builtin_amdgcn_mfma_f32_16x16x32_bf16(af[mi], bf[ni], acc[mi][ni], 0, 0, 0);
        }
        __syncthreads();
    }

    if (epi == 1) {
        u16* qk = (u16*)out0;
        const int colbase = n0 + wn * 64;
        if (colbase < 2048) {
            #pragma unroll
            for (int ni = 0; ni < 4; ni++) {
                const int col = colbase + ni * 16 + l16;
                const float bv = bf2f(bias[col]);
                #pragma unroll
                for (int mi = 0; mi < 4; mi++) {
                    const int row0 = m0 + wm * 64 + mi * 16 + quad * 4;
                    #pragma unroll
                    for (int r = 0; r < 4; r++)
                        qk[(size_t)(row0 + r) * 2048 + col] = f2bf(acc[mi][ni][r] + bv);
                }
            }
        } else {
            const int cp0 = colbase - 2048;
            #pragma unroll
            for (int ni = 0; ni < 4; ni++) {
                const int cp = cp0 + ni * 16 + l16;            // 0..1023
                const int h = cp >> 6, dh = cp & 63;
                const float bv = bf2f(bias[2048 + cp]);
                #pragma unroll
                for (int mi = 0; mi < 4; mi++) {
                    const int row0 = m0 + wm * 64 + mi * 16 + quad * 4;
                    const int bb = row0 >> 11, nn = row0 & 2047;
                    u32x2 pk;
                    pk.x = (u32)f2bf(acc[mi][ni][0] + bv) | ((u32)f2bf(acc[mi][ni][1] + bv) << 16);
                    pk.y = (u32)f2bf(acc[mi][ni][2] + bv) | ((u32)f2bf(acc[mi][ni][3] + bv) << 16);
                    *(u32x2*)&vt[(size_t)(((bb * 16 + h) * 64) + dh) * 2048 + nn] = pk;
                }
            }
        }
    } else {
        const bool f32o = (*mode != 0);
        #pragma unroll
        for (int ni = 0; ni < 4; ni++) {
            const int col = n0 + wn * 64 + ni * 16 + l16;
            #pragma unroll
            for (int mi = 0; mi < 4; mi++) {
                const int row0 = m0 + wm * 64 + mi * 16 + quad * 4;
                #pragma unroll
                for (int r = 0; r < 4; r++) {
                    const float val = acc[mi][ni][r];
                    if (f32o) ((float*)out0)[(size_t)(row0 + r) * 1024 + col] = val;
                    else      ((u16*)out0)[(size_t)(row0 + r) * 1024 + col]  = f2bf(val);
                }
            }
        }
    }
}

// ---------------------------------------------------------------- per-head LN over DH=64, in place
// q scale folds DH^-0.5 AND log2(e) (attn softmax runs in base-2 domain).
__global__ __launch_bounds__(256) void headln(u16* __restrict__ qk,
                                              const u16* __restrict__ qw, const u16* __restrict__ qb,
                                              const u16* __restrict__ kw, const u16* __restrict__ kb)
{
    const int isK = blockIdx.y;
    const u16* w = isK ? kw : qw;
    const u16* b = isK ? kb : qb;
    const float scale = isK ? 1.0f : 0.18033688011112042f;   // 0.125 * log2(e)
    const int wv = threadIdx.x >> 6, lane = threadIdx.x & 63;
    const int r = blockIdx.x * 4 + wv;
    u16* p = qk + (size_t)(r >> 4) * 2048 + isK * 1024 + (r & 15) * 64;
    float v = bf2f(p[lane]);
    float s = v, sq = v * v;
    #pragma unroll
    for (int off = 1; off < 64; off <<= 1) {
        s  += __shfl_xor(s,  off, 64);
        sq += __shfl_xor(sq, off, 64);
    }
    float mean = s * (1.0f / 64.0f);
    float var  = sq * (1.0f / 64.0f) - mean * mean;
    float rs   = rsqrtf(var + 1e-5f);
    p[lane] = f2bf(((v - mean) * rs * bf2f(w[lane]) + bf2f(b[lane])) * scale);
}

// ---------------------------------------------------------------- flash attention, O^T, fixed-max softmax
// grid (16, 64): x = 128-query tile, y = b*16+h. Wave handles 32 queries (2 groups of 16);
// all 4 waves share K/V tiles (64 keys/iter) staged manually with stride-72 rows
// (144 B -> 2-way bank aliasing only, free per m136; global_load_lds can't pad).
// Softmax in base-2 with FIXED max M=12 (|S| <= ||q||*||k|| = 1.443*8 = 11.54 after QK-LN,
// folded into mask constant) -> no running max, no rescale, no per-iter reductions.
// P round-trips wave-private LDS rows (reused g0/g1; in-order DS pipe, no barrier).
__global__ __launch_bounds__(256) void attn(const u16* __restrict__ qk, const u16* __restrict__ vt,
                                            const int* __restrict__ mask, u16* __restrict__ ctx)
{
    __shared__ __align__(16) float maskf[2048];     // 8 KB
    __shared__ __align__(16) u16 Ks[64 * 72];       // 9 KB  [j][dh]
    __shared__ __align__(16) u16 Vs[64 * 72];       // 9 KB  [dh][j]
    __shared__ __align__(16) u16 Ps[64 * 72];       // 9 KB  wave-private rows [i][j]
                                                    // total 35840 B -> 4 blocks/CU

    const int bh = blockIdx.y, b = bh >> 4, h = bh & 15;
    const int i0 = blockIdx.x * 128;
    const int tid = threadIdx.x, wv = tid >> 6, lane = tid & 63, quad = lane >> 4, l16 = lane & 15;

    for (int idx = tid; idx < 2048; idx += 256)
        maskf[idx] = mask[b * 2048 + idx] ? -12.0f : -1e9f;

    const u16* qbase = qk + (size_t)(b * 2048) * 2048 + h * 64;
    const u16* kbase = qbase + 1024;
    const u16* vbase = vt + (size_t)(bh * 64) * 2048;   // rows = dh, cols = n

    short8 qf[2][2];
    #pragma unroll
    for (int g = 0; g < 2; g++) {
        const int iw = i0 + wv * 32 + g * 16 + l16;
        qf[g][0] = *(const short8*)(qbase + (size_t)iw * 2048 + quad * 8);
        qf[g][1] = *(const short8*)(qbase + (size_t)iw * 2048 + 32 + quad * 8);
    }

    f32x4 O[2][4] = {};
    float l_lane[2] = {0.0f, 0.0f};
    u16* prow = &Ps[(wv * 16 + l16) * 72];

    const int sr = tid >> 3;          // staging row 0..31 (two passes cover 64)
    const int sc = (tid & 7) * 8;     // 16B chunk within 128B of row data

    for (int j0 = 0; j0 < 2048; j0 += 64) {
        // stage K [j][dh] and V^T [dh][j] with padded stride 72
        #pragma unroll
        for (int p = 0; p < 2; p++) {
            const int r = sr + p * 32;
            u32x4 kv = *(const u32x4*)(kbase + (size_t)(j0 + r) * 2048 + sc);
            u32x4 vv = *(const u32x4*)(vbase + (size_t)r * 2048 + j0 + sc);
            *(u32x4*)&Ks[r * 72 + sc] = kv;
            *(u32x4*)&Vs[r * 72 + sc] = vv;
        }
        __syncthreads();

        #pragma unroll
        for (int g = 0; g < 2; g++) {
            // S^T: C initialized with mask row (mask already includes -M)
            f32x4 sfr[4];
            #pragma unroll
            for (int sub = 0; sub < 4; sub++) {
                short8 kf0 = *(const short8*)&Ks[(sub * 16 + l16) * 72 + quad * 8];
                short8 kf1 = *(const short8*)&Ks[(sub * 16 + l16) * 72 + 32 + quad * 8];
                f32x4 sz = *(const f32x4*)&maskf[j0 + sub * 16 + quad * 4];
                sz = __builtin_amdgcn_mfma_f32_16x16x32_bf16(kf0, qf[g][0], sz, 0, 0, 0);
                sz = __builtin_amdgcn_mfma_f32_16x16x32_bf16(kf1, qf[g][1], sz, 0, 0, 0);
                sfr[sub] = sz;
            }
            // P = exp2(S + mask - M); accumulate l per lane (reduce over quads at end)
            float lp = 0.0f;
            #pragma unroll
            for (int sub = 0; sub < 4; sub++)
                #pragma unroll
                for (int r = 0; r < 4; r++) {
                    float e = exp2f(sfr[sub][r]);
                    sfr[sub][r] = e;
                    lp += e;
                }
            l_lane[g] += lp;

            // P -> wave-private LDS rows [i=l16][j]; trunc-pack
            #pragma unroll
            for (int sub = 0; sub < 4; sub++) {
                u32x2 pk;
                pk.x = pack_trunc(sfr[sub][0], sfr[sub][1]);
                pk.y = pack_trunc(sfr[sub][2], sfr[sub][3]);
                *(u32x2*)&prow[sub * 16 + quad * 4] = pk;
            }
            short8 pf0 = *(const short8*)&prow[quad * 8];
            short8 pf1 = *(const short8*)&prow[32 + quad * 8];

            // PV^T: O[dh][i] += Vt (A) x P^T (B)
            #pragma unroll
            for (int dht = 0; dht < 4; dht++) {
                short8 vf0 = *(const short8*)&Vs[(dht * 16 + l16) * 72 + quad * 8];
                short8 vf1 = *(const short8*)&Vs[(dht * 16 + l16) * 72 + 32 + quad * 8];
                O[g][dht] = __builtin_amdgcn_mfma_f32_16x16x32_bf16(vf0, pf0, O[g][dht], 0, 0, 0);
                O[g][dht] = __builtin_amdgcn_mfma_f32_16x16x32_bf16(vf1, pf1, O[g][dht], 0, 0, 0);
            }
        }
        __syncthreads();   // all waves done reading K/V before next stage overwrites
    }

    #pragma unroll
    for (int g = 0; g < 2; g++) {
        float l = l_lane[g];
        l += __shfl_xor(l, 16, 64);
        l += __shfl_xor(l, 32, 64);
        const float inv = l > 0.0f ? 1.0f / l : 0.0f;    // valid for query i=l16
        const int iw = i0 + wv * 32 + g * 16 + l16;
        u16* cb = ctx + (size_t)(b * 2048 + iw) * 1024 + h * 64;
        #pragma unroll
        for (int dht = 0; dht < 4; dht++) {
            u32x2 pk;
            pk.x = (u32)f2bf(O[g][dht][0] * inv) | ((u32)f2bf(O[g][dht][1] * inv) << 16);
            pk.y = (u32)f2bf(O[g][dht][2] * inv) | ((u32)f2bf(O[g][dht][3] * inv) << 16);
            *(u32x2*)(cb + dht * 16 + quad * 4) = pk;
        }
    }
}

// ----------------------------------------------------------------
extern "C" void kernel_launch(void* const* d_in, const int* in_sizes, int n_in,
                              void* d_out, int out_size, void* d_ws, size_t ws_size,
                              hipStream_t stream)
{
    const int* mask = (const int*)d_in[1];

    u16* ws = (u16*)d_ws;
    u16* xn  = ws;                      // [0, 8388608)
    u16* qkb = ws + 8388608;            // [8388608, 25165824)  [8192][2048]
    u16* vtb = ws + 25165824;           // [25165824, 33554432) [4][16][64][2048]
    u16* ctx = xn;                      // xn dead after QKV GEMM; reuse
    u16* cW  = ws + 33554432;           // Wq|Wk|Wv|Wo
    u16* cV  = ws + 37748736;           // vectors (5376)
    int* mode = (int*)(ws + 37754176);

    detect_mode<<<dim3(1), dim3(256), 0, stream>>>((const u16*)d_in[0], mode);

    SrcPtrs sp;
    for (int i = 0; i < 13; i++) sp.p[i] = d_in[i + 2];
    convert_params<<<dim3(16405), dim3(256), 0, stream>>>(sp, ws, mode);

    ln_kernel<<<dim3(8192), dim3(256), 0, stream>>>(d_in[0], cV + 0, cV + 1024, xn, mode);

    // fused QKV: N=3072, stacked W = cW (Wq|Wk|Wv), stacked bias = cV+2048 (bq|bk|bv)
    gemm128<<<dim3(64, 24), dim3(256), 0, stream>>>(xn, cW, cV + 2048, qkb, vtb, mode, 1, 3072);

    headln<<<dim3(32768, 2), dim3(256), 0, stream>>>(qkb, cV + 5120, cV + 5184, cV + 5248, cV + 5312);

    attn<<<dim3(16, 64), dim3(256), 0, stream>>>(qkb, vtb, mask, ctx);

    gemm128<<<dim3(64, 8), dim3(256), 0, stream>>>(ctx, cW + 3145728, nullptr, d_out, nullptr, mode, 2, 1024);
}

// Round 6
// 404.768 us; speedup vs baseline: 1.9389x; 1.1962x over previous
//
#include <hip/hip_runtime.h>
#include <hip/hip_bf16.h>
#include <cstdint>

typedef unsigned short u16;
typedef unsigned int   u32;
typedef __attribute__((ext_vector_type(8))) short short8;   // 8 bf16 (4 VGPRs) MFMA A/B frag
typedef __attribute__((ext_vector_type(4))) float f32x4;    // MFMA C/D frag / float4 load
typedef __attribute__((ext_vector_type(4))) u32  u32x4;     // 16B load/store
typedef __attribute__((ext_vector_type(2))) u32  u32x2;

#define DEV static __device__ __forceinline__

DEV float bf2f(u16 u){ u32 t = ((u32)u) << 16; float f; __builtin_memcpy(&f, &t, 4); return f; }
DEV u16 f2bf(float f){ u32 t; __builtin_memcpy(&t, &f, 4); return (u16)((t + 0x7fffu + ((t >> 16) & 1u)) >> 16); }

#if __has_builtin(__builtin_amdgcn_exp2f)
DEV float fast_exp2(float x){ return __builtin_amdgcn_exp2f(x); }
#else
DEV float fast_exp2(float x){ return exp2f(x); }
#endif

// pack hi16(x) | hi16(y)<<16  (truncation; P in [0,1])
DEV u32 pack_trunc(float x, float y){
    u32 tx, ty; __builtin_memcpy(&tx, &x, 4); __builtin_memcpy(&ty, &y, 4);
#if __has_builtin(__builtin_amdgcn_perm)
    return __builtin_amdgcn_perm(ty, tx, 0x07060302);   // bytes: [x2,x3,y2,y3]
#else
    return (tx >> 16) | (ty & 0xFFFF0000u);
#endif
}

// async global->LDS, 16B per lane. LDS dst must be wave-uniform; HW writes dst + lane*16.
DEV void gload_lds16(const void* g, void* l) {
    __builtin_amdgcn_global_load_lds((__attribute__((address_space(1))) void*)(g),
                                     (__attribute__((address_space(3))) void*)(l), 16, 0, 0);
}

// ---------------------------------------------------------------- dtype probe
__global__ __launch_bounds__(256) void detect_mode(const u16* __restrict__ x, int* __restrict__ mode)
{
    __shared__ int red[4];
    const int tid = threadIdx.x;
    int crazy = 0;
    for (int i = tid; i < 1024; i += 256) {
        u16 v = x[2 * i];
        int e = (v >> 7) & 0xFF;
        if (e >= 0x9F || (e > 0 && e <= 0x5F)) crazy++;
    }
    #pragma unroll
    for (int off = 1; off < 64; off <<= 1) crazy += __shfl_xor(crazy, off, 64);
    if ((tid & 63) == 0) red[tid >> 6] = crazy;
    __syncthreads();
    if (tid == 0) *mode = (red[0] + red[1] + red[2] + red[3] > 128) ? 1 : 0;
}

// ---------------------------------------------------------------- canonicalize params to bf16 in ws
struct SrcPtrs { const void* p[13]; };

__global__ __launch_bounds__(256) void convert_params(SrcPtrs sp, u16* __restrict__ ws,
                                                      const int* __restrict__ mode)
{
    const bool f = (*mode != 0);
    u16* cW = ws + 33554432;
    u16* cV = ws + 37748736;
    if (blockIdx.x < 16384) {
        const int i = blockIdx.x * 256 + threadIdx.x;          // 0..4194303
        const int t = i >> 20, off = i & 1048575;
        const void* src = (t == 0) ? sp.p[6] : (t == 1) ? sp.p[8] : (t == 2) ? sp.p[10] : sp.p[12];
        cW[i] = f ? f2bf(((const float*)src)[off]) : ((const u16*)src)[off];
    } else {
        const int j = (blockIdx.x - 16384) * 256 + threadIdx.x;
        if (j >= 5376) return;
        const void* src; int off;
        if      (j < 1024) { src = sp.p[0];  off = j; }
        else if (j < 2048) { src = sp.p[1];  off = j - 1024; }
        else if (j < 3072) { src = sp.p[7];  off = j - 2048; }
        else if (j < 4096) { src = sp.p[9];  off = j - 3072; }
        else if (j < 5120) { src = sp.p[11]; off = j - 4096; }
        else { int m = j - 5120; src = sp.p[2 + (m >> 6)]; off = m & 63; }
        cV[j] = f ? f2bf(((const float*)src)[off]) : ((const u16*)src)[off];
    }
}

// ---------------------------------------------------------------- LayerNorm over D=1024 (dual-mode x)
__global__ __launch_bounds__(256) void ln_kernel(const void* __restrict__ x,
                                                 const u16* __restrict__ w,
                                                 const u16* __restrict__ b,
                                                 u16* __restrict__ xn,
                                                 const int* __restrict__ mode)
{
    const int row = blockIdx.x;
    const int tid = threadIdx.x;
    const int wv = tid >> 6, lane = tid & 63;

    float v0, v1, v2, v3;
    if (*mode) {
        f32x4 r = *((const f32x4*)((const float*)x + row * 1024) + tid);
        v0 = r[0]; v1 = r[1]; v2 = r[2]; v3 = r[3];
    } else {
        u32x2 raw = *(const u32x2*)((const u16*)x + row * 1024 + tid * 4);
        v0 = bf2f((u16)(raw.x & 0xffff)); v1 = bf2f((u16)(raw.x >> 16));
        v2 = bf2f((u16)(raw.y & 0xffff)); v3 = bf2f((u16)(raw.y >> 16));
    }
    float s  = v0 + v1 + v2 + v3;
    float sq = v0*v0 + v1*v1 + v2*v2 + v3*v3;
    #pragma unroll
    for (int off = 1; off < 64; off <<= 1) {
        s  += __shfl_xor(s,  off, 64);
        sq += __shfl_xor(sq, off, 64);
    }
    __shared__ float red[8];
    if (lane == 0) { red[wv] = s; red[4 + wv] = sq; }
    __syncthreads();
    float ts = red[0] + red[1] + red[2] + red[3];
    float tq = red[4] + red[5] + red[6] + red[7];
    float mean = ts * (1.0f / 1024.0f);
    float var  = tq * (1.0f / 1024.0f) - mean * mean;
    float rs   = rsqrtf(var + 1e-5f);

    float y0 = (v0 - mean) * rs * bf2f(w[tid*4+0]) + bf2f(b[tid*4+0]);
    float y1 = (v1 - mean) * rs * bf2f(w[tid*4+1]) + bf2f(b[tid*4+1]);
    float y2 = (v2 - mean) * rs * bf2f(w[tid*4+2]) + bf2f(b[tid*4+2]);
    float y3 = (v3 - mean) * rs * bf2f(w[tid*4+3]) + bf2f(b[tid*4+3]);
    u32x2 out;
    out.x = (u32)f2bf(y0) | ((u32)f2bf(y1) << 16);
    out.y = (u32)f2bf(y2) | ((u32)f2bf(y3) << 16);
    *(u32x2*)(xn + row * 1024 + tid * 4) = out;
}

// ---------------------------------------------------------------- m97-class GEMM: C = A[8192][1024] @ W[N][1024]^T
// 128x128 tile, BK=64, global_load_lds(16B) staging, 4 waves each 64x64 (4x4 of 16x16x32).
// epi=1 (QKV fused): wave's 64 cols = exactly one head.
//   cols<2048 -> +bias, per-head LN (qn/kn) fused (reduce over l16 within quad), q also
//                scaled by 0.125*log2e -> qk[8192][2048] bf16.
//   cols>=2048 -> +bias -> vt[b][h][dh][n].
// epi=2: final out — out0 as f32 (if *mode) else bf16, no bias.
__global__ __launch_bounds__(256) void gemm128(const u16* __restrict__ A,
                                               const u16* __restrict__ W,
                                               const u16* __restrict__ bias,
                                               void* __restrict__ out0,
                                               u16* __restrict__ vt,
                                               const u16* __restrict__ qnw, const u16* __restrict__ qnb,
                                               const u16* __restrict__ knw, const u16* __restrict__ knb,
                                               const int* __restrict__ mode,
                                               int epi, int N)
{
    __shared__ u16 As[128 * 64];
    __shared__ u16 Bs[128 * 64];
    const int tid = threadIdx.x;
    const int m0 = blockIdx.x * 128, n0 = blockIdx.y * 128;
    const int wv = tid >> 6, lane = tid & 63, quad = lane >> 4, l16 = lane & 15;
    const int wm = wv & 1, wn = wv >> 1;

    f32x4 acc[4][4] = {};

    const int srow = tid >> 3, scol = (tid & 7) * 8;
    const u16* Ap = A + (size_t)(m0 + srow) * 1024 + scol;
    const u16* Wp = W + (size_t)(n0 + srow) * 1024 + scol;

    for (int k0 = 0; k0 < 1024; k0 += 64) {
        #pragma unroll
        for (int i = 0; i < 4; i++)
            gload_lds16(Ap + k0 + (size_t)i * 32 * 1024, &As[i * 2048 + wv * 512]);
        #pragma unroll
        for (int i = 0; i < 4; i++)
            gload_lds16(Wp + k0 + (size_t)i * 32 * 1024, &Bs[i * 2048 + wv * 512]);
        __syncthreads();
        #pragma unroll
        for (int kh = 0; kh < 64; kh += 32) {
            short8 af[4], bf[4];
            #pragma unroll
            for (int mi = 0; mi < 4; mi++)
                af[mi] = *(const short8*)&As[(wm * 64 + mi * 16 + l16) * 64 + kh + quad * 8];
            #pragma unroll
            for (int ni = 0; ni < 4; ni++)
                bf[ni] = *(const short8*)&Bs[(wn * 64 + ni * 16 + l16) * 64 + kh + quad * 8];
            #pragma unroll
            for (int mi = 0; mi < 4; mi++)
                #pragma unroll
                for (int ni = 0; ni < 4; ni++)
                    acc[mi][ni] = __builtin_amdgcn_mfma_f32_16x16x32_bf16(af[mi], bf[ni], acc[mi][ni], 0, 0, 0);
        }
        __syncthreads();
    }

    if (epi == 1) {
        const int colbase = n0 + wn * 64;
        if (colbase < 2048) {
            const bool isK = colbase >= 1024;
            const u16* lw = isK ? knw : qnw;
            const u16* lb = isK ? knb : qnb;
            const float scale = isK ? 1.0f : 0.18033688011112042f;   // 0.125 * log2(e)
            float lnw[4], lnb2[4], bv[4];
            #pragma unroll
            for (int ni = 0; ni < 4; ni++) {
                const int dh = ni * 16 + l16;
                lnw[ni] = bf2f(lw[dh]); lnb2[ni] = bf2f(lb[dh]); bv[ni] = bf2f(bias[colbase + dh]);
            }
            u16* qk = (u16*)out0;
            #pragma unroll
            for (int mi = 0; mi < 4; mi++) {
                #pragma unroll
                for (int r = 0; r < 4; r++) {
                    float v[4];
                    float s = 0.0f, sq = 0.0f;
                    #pragma unroll
                    for (int ni = 0; ni < 4; ni++) {
                        v[ni] = acc[mi][ni][r] + bv[ni];
                        s += v[ni]; sq += v[ni] * v[ni];
                    }
                    #pragma unroll
                    for (int off = 1; off < 16; off <<= 1) {
                        s  += __shfl_xor(s,  off, 64);
                        sq += __shfl_xor(sq, off, 64);
                    }
                    const float mean = s * (1.0f / 64.0f);
                    const float var  = sq * (1.0f / 64.0f) - mean * mean;
                    const float rs   = rsqrtf(var + 1e-5f);
                    const int row = m0 + wm * 64 + mi * 16 + quad * 4 + r;
                    #pragma unroll
                    for (int ni = 0; ni < 4; ni++)
                        qk[(size_t)row * 2048 + colbase + ni * 16 + l16] =
                            f2bf(((v[ni] - mean) * rs * lnw[ni] + lnb2[ni]) * scale);
                }
            }
        } else {
            const int cp0 = colbase - 2048;
            #pragma unroll
            for (int ni = 0; ni < 4; ni++) {
                const int cp = cp0 + ni * 16 + l16;            // 0..1023
                const int h = cp >> 6, dh = cp & 63;
                const float bvv = bf2f(bias[2048 + cp]);
                #pragma unroll
                for (int mi = 0; mi < 4; mi++) {
                    const int row0 = m0 + wm * 64 + mi * 16 + quad * 4;
                    const int bb = row0 >> 11, nn = row0 & 2047;
                    u32x2 pk;
                    pk.x = (u32)f2bf(acc[mi][ni][0] + bvv) | ((u32)f2bf(acc[mi][ni][1] + bvv) << 16);
                    pk.y = (u32)f2bf(acc[mi][ni][2] + bvv) | ((u32)f2bf(acc[mi][ni][3] + bvv) << 16);
                    *(u32x2*)&vt[(size_t)(((bb * 16 + h) * 64) + dh) * 2048 + nn] = pk;
                }
            }
        }
    } else {
        const bool f32o = (*mode != 0);
        #pragma unroll
        for (int ni = 0; ni < 4; ni++) {
            const int col = n0 + wn * 64 + ni * 16 + l16;
            #pragma unroll
            for (int mi = 0; mi < 4; mi++) {
                const int row0 = m0 + wm * 64 + mi * 16 + quad * 4;
                #pragma unroll
                for (int r = 0; r < 4; r++) {
                    const float val = acc[mi][ni][r];
                    if (f32o) ((float*)out0)[(size_t)(row0 + r) * 1024 + col] = val;
                    else      ((u16*)out0)[(size_t)(row0 + r) * 1024 + col]  = f2bf(val);
                }
            }
        }
    }
}

// ---------------------------------------------------------------- flash attention, O^T, fixed-max softmax
// grid (16, 64): 128-query tile, y = b*16+h. Wave = 32 queries (2 groups of 16), g interleaved
// inside each phase so K-frags / V-frags / mask rows are read from LDS ONCE per iter.
// K/V staged via async global_load_lds (16B) with XOR column swizzle slot=(chunk+row)&7
// (stride-64 rows, conflict pattern equal to padded). Softmax base-2, fixed max M=12
// (|S|<=11.54 after QK-LN), mask carries -12/-1e9 as MFMA C-init. P round-trips
// wave-private LDS (2 g-halves) into the B-frag of P^T; no barrier in the P path.
__global__ __launch_bounds__(256, 3) void attn(const u16* __restrict__ qk, const u16* __restrict__ vt,
                                               const int* __restrict__ mask, u16* __restrict__ ctx)
{
    __shared__ __align__(16) float maskf[2048];     // 8 KB
    __shared__ __align__(16) u16 Ks[64 * 64];       // 8 KB  [j][dh] swizzled
    __shared__ __align__(16) u16 Vs[64 * 64];       // 8 KB  [dh][j] swizzled
    __shared__ __align__(16) u16 Ps[128 * 72];      // 18 KB [g*64 + wv*16 + i][j], stride 72
                                                    // total 43008 B -> 3 blocks/CU

    const int bh = blockIdx.y, b = bh >> 4, h = bh & 15;
    const int i0 = blockIdx.x * 128;
    const int tid = threadIdx.x, wv = tid >> 6, lane = tid & 63, quad = lane >> 4, l16 = lane & 15;

    for (int idx = tid; idx < 2048; idx += 256)
        maskf[idx] = mask[b * 2048 + idx] ? -12.0f : -1e9f;

    const u16* qbase = qk + (size_t)(b * 2048) * 2048 + h * 64;
    const u16* kbase = qbase + 1024;
    const u16* vbase = vt + (size_t)(bh * 64) * 2048;   // rows = dh, cols = n

    short8 qf[2][2];
    #pragma unroll
    for (int g = 0; g < 2; g++) {
        const int iw = i0 + wv * 32 + g * 16 + l16;
        qf[g][0] = *(const short8*)(qbase + (size_t)iw * 2048 + quad * 8);
        qf[g][1] = *(const short8*)(qbase + (size_t)iw * 2048 + 32 + quad * 8);
    }

    f32x4 O[2][4] = {};
    float l_lane[2] = {0.0f, 0.0f};

    // staging: lane -> (row-in-8 sr, LDS slot ss); source chunk = (ss - sr) & 7 (XOR swizzle)
    const int sr = lane >> 3, ss = lane & 7;
    const int sck = ((ss - sr) & 7) * 8;
    const u16* kp0 = kbase + (size_t)(wv * 16 +      sr) * 2048 + sck;
    const u16* kp1 = kbase + (size_t)(wv * 16 + 8  + sr) * 2048 + sck;
    const u16* vp0 = vbase + (size_t)(wv * 16 +      sr) * 2048 + sck;
    const u16* vp1 = vbase + (size_t)(wv * 16 + 8  + sr) * 2048 + sck;

    // loop-invariant LDS frag bases (swizzled)
    const int swz0 = ((quad     + l16) & 7) * 8;
    const int swz1 = ((quad + 4 + l16) & 7) * 8;
    const u16* kb0 = &Ks[l16 * 64 + swz0];
    const u16* kb1 = &Ks[l16 * 64 + swz1];
    const u16* vb0 = &Vs[l16 * 64 + swz0];
    const u16* vb1 = &Vs[l16 * 64 + swz1];
    u16* pw = &Ps[(wv * 16 + l16) * 72];

    for (int j0 = 0; j0 < 2048; j0 += 64) {
        gload_lds16(kp0, &Ks[(wv * 16    ) * 64]);
        gload_lds16(kp1, &Ks[(wv * 16 + 8) * 64]);
        gload_lds16(vp0, &Vs[(wv * 16    ) * 64]);
        gload_lds16(vp1, &Vs[(wv * 16 + 8) * 64]);
        kp0 += 64 * 2048; kp1 += 64 * 2048; vp0 += 64; vp1 += 64;
        __syncthreads();   // vmcnt drain: tiles (and, iter 0, maskf) ready

        // S phase: K-frags and mask rows read once, used by both g
        f32x4 sfr[2][4];
        #pragma unroll
        for (int sub = 0; sub < 4; sub++) {
            short8 kf0 = *(const short8*)(kb0 + sub * 1024);
            short8 kf1 = *(const short8*)(kb1 + sub * 1024);
            f32x4 mrow = *(const f32x4*)&maskf[j0 + sub * 16 + quad * 4];
            #pragma unroll
            for (int g = 0; g < 2; g++) {
                f32x4 sz = mrow;
                sz = __builtin_amdgcn_mfma_f32_16x16x32_bf16(kf0, qf[g][0], sz, 0, 0, 0);
                sz = __builtin_amdgcn_mfma_f32_16x16x32_bf16(kf1, qf[g][1], sz, 0, 0, 0);
                sfr[g][sub] = sz;
            }
        }

        // softmax (fixed max, base-2) + P write, both g
        #pragma unroll
        for (int g = 0; g < 2; g++) {
            float lp = 0.0f;
            #pragma unroll
            for (int sub = 0; sub < 4; sub++)
                #pragma unroll
                for (int r = 0; r < 4; r++) {
                    float e = fast_exp2(sfr[g][sub][r]);
                    sfr[g][sub][r] = e;
                    lp += e;
                }
            l_lane[g] += lp;
            #pragma unroll
            for (int sub = 0; sub < 4; sub++) {
                u32x2 pk;
                pk.x = pack_trunc(sfr[g][sub][0], sfr[g][sub][1]);
                pk.y = pack_trunc(sfr[g][sub][2], sfr[g][sub][3]);
                *(u32x2*)(pw + g * 4608 + sub * 16 + quad * 4) = pk;
            }
        }

        // P frags (per g), then PV with V-frags read once
        short8 pf[2][2];
        #pragma unroll
        for (int g = 0; g < 2; g++) {
            pf[g][0] = *(const short8*)(pw + g * 4608 + quad * 8);
            pf[g][1] = *(const short8*)(pw + g * 4608 + 32 + quad * 8);
        }
        #pragma unroll
        for (int dht = 0; dht < 4; dht++) {
            short8 vf0 = *(const short8*)(vb0 + dht * 1024);
            short8 vf1 = *(const short8*)(vb1 + dht * 1024);
            #pragma unroll
            for (int g = 0; g < 2; g++) {
                O[g][dht] = __builtin_amdgcn_mfma_f32_16x16x32_bf16(vf0, pf[g][0], O[g][dht], 0, 0, 0);
                O[g][dht] = __builtin_amdgcn_mfma_f32_16x16x32_bf16(vf1, pf[g][1], O[g][dht], 0, 0, 0);
            }
        }
        __syncthreads();   // all waves done reading K/V before next stage overwrites
    }

    #pragma unroll
    for (int g = 0; g < 2; g++) {
        float l = l_lane[g];
        l += __shfl_xor(l, 16, 64);
        l += __shfl_xor(l, 32, 64);
        const float inv = l > 0.0f ? 1.0f / l : 0.0f;    // valid for query i=l16
        const int iw = i0 + wv * 32 + g * 16 + l16;
        u16* cb = ctx + (size_t)(b * 2048 + iw) * 1024 + h * 64;
        #pragma unroll
        for (int dht = 0; dht < 4; dht++) {
            u32x2 pk;
            pk.x = (u32)f2bf(O[g][dht][0] * inv) | ((u32)f2bf(O[g][dht][1] * inv) << 16);
            pk.y = (u32)f2bf(O[g][dht][2] * inv) | ((u32)f2bf(O[g][dht][3] * inv) << 16);
            *(u32x2*)(cb + dht * 16 + quad * 4) = pk;
        }
    }
}

// ----------------------------------------------------------------
extern "C" void kernel_launch(void* const* d_in, const int* in_sizes, int n_in,
                              void* d_out, int out_size, void* d_ws, size_t ws_size,
                              hipStream_t stream)
{
    const int* mask = (const int*)d_in[1];

    u16* ws = (u16*)d_ws;
    u16* xn  = ws;                      // [0, 8388608)
    u16* qkb = ws + 8388608;            // [8388608, 25165824)  [8192][2048]
    u16* vtb = ws + 25165824;           // [25165824, 33554432) [4][16][64][2048]
    u16* ctx = xn;                      // xn dead after QKV GEMM; reuse
    u16* cW  = ws + 33554432;           // Wq|Wk|Wv|Wo
    u16* cV  = ws + 37748736;           // vectors (5376)
    int* mode = (int*)(ws + 37754176);

    detect_mode<<<dim3(1), dim3(256), 0, stream>>>((const u16*)d_in[0], mode);

    SrcPtrs sp;
    for (int i = 0; i < 13; i++) sp.p[i] = d_in[i + 2];
    convert_params<<<dim3(16405), dim3(256), 0, stream>>>(sp, ws, mode);

    ln_kernel<<<dim3(8192), dim3(256), 0, stream>>>(d_in[0], cV + 0, cV + 1024, xn, mode);

    // fused QKV + head-LN: N=3072, stacked W = cW (Wq|Wk|Wv), stacked bias = cV+2048
    gemm128<<<dim3(64, 24), dim3(256), 0, stream>>>(xn, cW, cV + 2048, qkb, vtb,
                                                    cV + 5120, cV + 5184, cV + 5248, cV + 5312,
                                                    mode, 1, 3072);

    attn<<<dim3(16, 64), dim3(256), 0, stream>>>(qkb, vtb, mask, ctx);

    gemm128<<<dim3(64, 8), dim3(256), 0, stream>>>(ctx, cW + 3145728, nullptr, d_out, nullptr,
                                                   nullptr, nullptr, nullptr, nullptr,
                                                   mode, 2, 1024);
}

// Round 7
// 313.901 us; speedup vs baseline: 2.5001x; 1.2895x over previous
//
#include <hip/hip_runtime.h>
#include <hip/hip_bf16.h>
#include <cstdint>

typedef unsigned short u16;
typedef unsigned int   u32;
typedef __attribute__((ext_vector_type(8))) short short8;   // 8 bf16 (4 VGPRs) MFMA A/B frag
typedef __attribute__((ext_vector_type(4))) float f32x4;    // MFMA C/D frag / float4 load
typedef __attribute__((ext_vector_type(4))) u32  u32x4;     // 16B load/store
typedef __attribute__((ext_vector_type(2))) u32  u32x2;

#define DEV static __device__ __forceinline__

DEV float bf2f(u16 u){ u32 t = ((u32)u) << 16; float f; __builtin_memcpy(&f, &t, 4); return f; }
DEV u16 f2bf(float f){ u32 t; __builtin_memcpy(&t, &f, 4); return (u16)((t + 0x7fffu + ((t >> 16) & 1u)) >> 16); }

#if __has_builtin(__builtin_amdgcn_exp2f)
DEV float fast_exp2(float x){ return __builtin_amdgcn_exp2f(x); }
#else
DEV float fast_exp2(float x){ return exp2f(x); }
#endif

// pack hi16(x) | hi16(y)<<16  (truncation; P in [0,1])
DEV u32 pack_trunc(float x, float y){
    u32 tx, ty; __builtin_memcpy(&tx, &x, 4); __builtin_memcpy(&ty, &y, 4);
#if __has_builtin(__builtin_amdgcn_perm)
    return __builtin_amdgcn_perm(ty, tx, 0x07060302);   // bytes: [x2,x3,y2,y3]
#else
    return (tx >> 16) | (ty & 0xFFFF0000u);
#endif
}

// async global->LDS, 16B per lane. LDS dst must be wave-uniform; HW writes dst + lane*16.
DEV void gload_lds16(const void* g, void* l) {
    __builtin_amdgcn_global_load_lds((__attribute__((address_space(1))) void*)(g),
                                     (__attribute__((address_space(3))) void*)(l), 16, 0, 0);
}

// ---------------------------------------------------------------- dtype probe
__global__ __launch_bounds__(256) void detect_mode(const u16* __restrict__ x, int* __restrict__ mode)
{
    __shared__ int red[4];
    const int tid = threadIdx.x;
    int crazy = 0;
    for (int i = tid; i < 1024; i += 256) {
        u16 v = x[2 * i];
        int e = (v >> 7) & 0xFF;
        if (e >= 0x9F || (e > 0 && e <= 0x5F)) crazy++;
    }
    #pragma unroll
    for (int off = 1; off < 64; off <<= 1) crazy += __shfl_xor(crazy, off, 64);
    if ((tid & 63) == 0) red[tid >> 6] = crazy;
    __syncthreads();
    if (tid == 0) *mode = (red[0] + red[1] + red[2] + red[3] > 128) ? 1 : 0;
}

// ---------------------------------------------------------------- canonicalize params to bf16 in ws
struct SrcPtrs { const void* p[13]; };

__global__ __launch_bounds__(256) void convert_params(SrcPtrs sp, u16* __restrict__ ws,
                                                      const int* __restrict__ mode)
{
    const bool f = (*mode != 0);
    u16* cW = ws + 33554432;
    u16* cV = ws + 37748736;
    if (blockIdx.x < 16384) {
        const int i = blockIdx.x * 256 + threadIdx.x;          // 0..4194303
        const int t = i >> 20, off = i & 1048575;
        const void* src = (t == 0) ? sp.p[6] : (t == 1) ? sp.p[8] : (t == 2) ? sp.p[10] : sp.p[12];
        cW[i] = f ? f2bf(((const float*)src)[off]) : ((const u16*)src)[off];
    } else {
        const int j = (blockIdx.x - 16384) * 256 + threadIdx.x;
        if (j >= 5376) return;
        const void* src; int off;
        if      (j < 1024) { src = sp.p[0];  off = j; }
        else if (j < 2048) { src = sp.p[1];  off = j - 1024; }
        else if (j < 3072) { src = sp.p[7];  off = j - 2048; }
        else if (j < 4096) { src = sp.p[9];  off = j - 3072; }
        else if (j < 5120) { src = sp.p[11]; off = j - 4096; }
        else { int m = j - 5120; src = sp.p[2 + (m >> 6)]; off = m & 63; }
        cV[j] = f ? f2bf(((const float*)src)[off]) : ((const u16*)src)[off];
    }
}

// ---------------------------------------------------------------- LayerNorm over D=1024 (dual-mode x)
__global__ __launch_bounds__(256) void ln_kernel(const void* __restrict__ x,
                                                 const u16* __restrict__ w,
                                                 const u16* __restrict__ b,
                                                 u16* __restrict__ xn,
                                                 const int* __restrict__ mode)
{
    const int row = blockIdx.x;
    const int tid = threadIdx.x;
    const int wv = tid >> 6, lane = tid & 63;

    float v0, v1, v2, v3;
    if (*mode) {
        f32x4 r = *((const f32x4*)((const float*)x + row * 1024) + tid);
        v0 = r[0]; v1 = r[1]; v2 = r[2]; v3 = r[3];
    } else {
        u32x2 raw = *(const u32x2*)((const u16*)x + row * 1024 + tid * 4);
        v0 = bf2f((u16)(raw.x & 0xffff)); v1 = bf2f((u16)(raw.x >> 16));
        v2 = bf2f((u16)(raw.y & 0xffff)); v3 = bf2f((u16)(raw.y >> 16));
    }
    float s  = v0 + v1 + v2 + v3;
    float sq = v0*v0 + v1*v1 + v2*v2 + v3*v3;
    #pragma unroll
    for (int off = 1; off < 64; off <<= 1) {
        s  += __shfl_xor(s,  off, 64);
        sq += __shfl_xor(sq, off, 64);
    }
    __shared__ float red[8];
    if (lane == 0) { red[wv] = s; red[4 + wv] = sq; }
    __syncthreads();
    float ts = red[0] + red[1] + red[2] + red[3];
    float tq = red[4] + red[5] + red[6] + red[7];
    float mean = ts * (1.0f / 1024.0f);
    float var  = tq * (1.0f / 1024.0f) - mean * mean;
    float rs   = rsqrtf(var + 1e-5f);

    float y0 = (v0 - mean) * rs * bf2f(w[tid*4+0]) + bf2f(b[tid*4+0]);
    float y1 = (v1 - mean) * rs * bf2f(w[tid*4+1]) + bf2f(b[tid*4+1]);
    float y2 = (v2 - mean) * rs * bf2f(w[tid*4+2]) + bf2f(b[tid*4+2]);
    float y3 = (v3 - mean) * rs * bf2f(w[tid*4+3]) + bf2f(b[tid*4+3]);
    u32x2 out;
    out.x = (u32)f2bf(y0) | ((u32)f2bf(y1) << 16);
    out.y = (u32)f2bf(y2) | ((u32)f2bf(y3) << 16);
    *(u32x2*)(xn + row * 1024 + tid * 4) = out;
}

// ---------------------------------------------------------------- m97-class GEMM + XOR bank swizzle
// C = A[8192][1024] @ W[N][1024]^T. 128x128 tile, BK=64, global_load_lds(16B) staging.
// LDS rows stride 64 elems (128 B = 32 banks); chunk c (16B) of row R stored at slot (c+R)&7
// via SOURCE-side swizzle (DMA dst can't scatter). Reads use slot=((quad+4*kh+l16)&7)*8:
// 8 lanes per 4-bank group x 8 groups in parallel = LDS bandwidth floor, no conflict penalty.
// __launch_bounds__(256,4): cap 128 VGPR -> 4 blocks/CU.
// epi=1 (QKV fused): wave's 64 cols = one head. cols<2048 -> +bias, fused head-LN (+q scale)
//   -> qk[8192][2048]; cols>=2048 -> +bias -> vt[b][h][dh][n].
// epi=2: final out — f32 (if *mode) else bf16, no bias.
__global__ __launch_bounds__(256, 4) void gemm128(const u16* __restrict__ A,
                                                  const u16* __restrict__ W,
                                                  const u16* __restrict__ bias,
                                                  void* __restrict__ out0,
                                                  u16* __restrict__ vt,
                                                  const u16* __restrict__ qnw, const u16* __restrict__ qnb,
                                                  const u16* __restrict__ knw, const u16* __restrict__ knb,
                                                  const int* __restrict__ mode,
                                                  int epi, int N)
{
    __shared__ u16 As[128 * 64];
    __shared__ u16 Bs[128 * 64];
    const int tid = threadIdx.x;
    const int m0 = blockIdx.x * 128, n0 = blockIdx.y * 128;
    const int wv = tid >> 6, lane = tid & 63, quad = lane >> 4, l16 = lane & 15;
    const int wm = wv & 1, wn = wv >> 1;

    f32x4 acc[4][4] = {};

    // staging: lane l covers LDS row (l>>3), slot (l&7); source chunk = ((l&7)-(l>>3))&7
    const int srow = tid >> 3;
    const int scol = (((tid & 7) - (srow & 7)) & 7) * 8;
    const u16* Ap = A + (size_t)(m0 + srow) * 1024 + scol;
    const u16* Wp = W + (size_t)(n0 + srow) * 1024 + scol;

    // read-side swizzled offsets (row&7 == l16&7 for all frag rows)
    const int swz0 = ((quad     + l16) & 7) * 8;   // kh half 0: chunk quad
    const int swz1 = ((quad + 4 + l16) & 7) * 8;   // kh half 1: chunk quad+4

    for (int k0 = 0; k0 < 1024; k0 += 64) {
        #pragma unroll
        for (int i = 0; i < 4; i++)
            gload_lds16(Ap + k0 + (size_t)i * 32 * 1024, &As[i * 2048 + wv * 512]);
        #pragma unroll
        for (int i = 0; i < 4; i++)
            gload_lds16(Wp + k0 + (size_t)i * 32 * 1024, &Bs[i * 2048 + wv * 512]);
        __syncthreads();
        #pragma unroll
        for (int kh = 0; kh < 2; kh++) {
            const int sw = kh ? swz1 : swz0;
            short8 af[4], bf[4];
            #pragma unroll
            for (int mi = 0; mi < 4; mi++)
                af[mi] = *(const short8*)&As[(wm * 64 + mi * 16 + l16) * 64 + sw];
            #pragma unroll
            for (int ni = 0; ni < 4; ni++)
                bf[ni] = *(const short8*)&Bs[(wn * 64 + ni * 16 + l16) * 64 + sw];
            #pragma unroll
            for (int mi = 0; mi < 4; mi++)
                #pragma unroll
                for (int ni = 0; ni < 4; ni++)
                    acc[mi][ni] = __builtin_amdgcn_mfma_f32_16x16x32_bf16(af[mi], bf[ni], acc[mi][ni], 0, 0, 0);
        }
        __syncthreads();
    }

    if (epi == 1) {
        const int colbase = n0 + wn * 64;
        if (colbase < 2048) {
            const bool isK = colbase >= 1024;
            const u16* lw = isK ? knw : qnw;
            const u16* lb = isK ? knb : qnb;
            const float scale = isK ? 1.0f : 0.18033688011112042f;   // 0.125 * log2(e)
            float lnw[4], lnb2[4], bv[4];
            #pragma unroll
            for (int ni = 0; ni < 4; ni++) {
                const int dh = ni * 16 + l16;
                lnw[ni] = bf2f(lw[dh]); lnb2[ni] = bf2f(lb[dh]); bv[ni] = bf2f(bias[colbase + dh]);
            }
            u16* qk = (u16*)out0;
            #pragma unroll
            for (int mi = 0; mi < 4; mi++) {
                #pragma unroll
                for (int r = 0; r < 4; r++) {
                    float v[4];
                    float s = 0.0f, sq = 0.0f;
                    #pragma unroll
                    for (int ni = 0; ni < 4; ni++) {
                        v[ni] = acc[mi][ni][r] + bv[ni];
                        s += v[ni]; sq += v[ni] * v[ni];
                    }
                    #pragma unroll
                    for (int off = 1; off < 16; off <<= 1) {
                        s  += __shfl_xor(s,  off, 64);
                        sq += __shfl_xor(sq, off, 64);
                    }
                    const float mean = s * (1.0f / 64.0f);
                    const float var  = sq * (1.0f / 64.0f) - mean * mean;
                    const float rs   = rsqrtf(var + 1e-5f);
                    const int row = m0 + wm * 64 + mi * 16 + quad * 4 + r;
                    #pragma unroll
                    for (int ni = 0; ni < 4; ni++)
                        qk[(size_t)row * 2048 + colbase + ni * 16 + l16] =
                            f2bf(((v[ni] - mean) * rs * lnw[ni] + lnb2[ni]) * scale);
                }
            }
        } else {
            const int cp0 = colbase - 2048;
            #pragma unroll
            for (int ni = 0; ni < 4; ni++) {
                const int cp = cp0 + ni * 16 + l16;            // 0..1023
                const int h = cp >> 6, dh = cp & 63;
                const float bvv = bf2f(bias[2048 + cp]);
                #pragma unroll
                for (int mi = 0; mi < 4; mi++) {
                    const int row0 = m0 + wm * 64 + mi * 16 + quad * 4;
                    const int bb = row0 >> 11, nn = row0 & 2047;
                    u32x2 pk;
                    pk.x = (u32)f2bf(acc[mi][ni][0] + bvv) | ((u32)f2bf(acc[mi][ni][1] + bvv) << 16);
                    pk.y = (u32)f2bf(acc[mi][ni][2] + bvv) | ((u32)f2bf(acc[mi][ni][3] + bvv) << 16);
                    *(u32x2*)&vt[(size_t)(((bb * 16 + h) * 64) + dh) * 2048 + nn] = pk;
                }
            }
        }
    } else {
        const bool f32o = (*mode != 0);
        #pragma unroll
        for (int ni = 0; ni < 4; ni++) {
            const int col = n0 + wn * 64 + ni * 16 + l16;
            #pragma unroll
            for (int mi = 0; mi < 4; mi++) {
                const int row0 = m0 + wm * 64 + mi * 16 + quad * 4;
                #pragma unroll
                for (int r = 0; r < 4; r++) {
                    const float val = acc[mi][ni][r];
                    if (f32o) ((float*)out0)[(size_t)(row0 + r) * 1024 + col] = val;
                    else      ((u16*)out0)[(size_t)(row0 + r) * 1024 + col]  = f2bf(val);
                }
            }
        }
    }
}

// ---------------------------------------------------------------- flash attention, O^T, fixed-max softmax
// (unchanged from r6 — no longer the top dispatch)
__global__ __launch_bounds__(256, 3) void attn(const u16* __restrict__ qk, const u16* __restrict__ vt,
                                               const int* __restrict__ mask, u16* __restrict__ ctx)
{
    __shared__ __align__(16) float maskf[2048];     // 8 KB
    __shared__ __align__(16) u16 Ks[64 * 64];       // 8 KB  [j][dh] swizzled
    __shared__ __align__(16) u16 Vs[64 * 64];       // 8 KB  [dh][j] swizzled
    __shared__ __align__(16) u16 Ps[128 * 72];      // 18 KB [g*64 + wv*16 + i][j], stride 72

    const int bh = blockIdx.y, b = bh >> 4, h = bh & 15;
    const int i0 = blockIdx.x * 128;
    const int tid = threadIdx.x, wv = tid >> 6, lane = tid & 63, quad = lane >> 4, l16 = lane & 15;

    for (int idx = tid; idx < 2048; idx += 256)
        maskf[idx] = mask[b * 2048 + idx] ? -12.0f : -1e9f;

    const u16* qbase = qk + (size_t)(b * 2048) * 2048 + h * 64;
    const u16* kbase = qbase + 1024;
    const u16* vbase = vt + (size_t)(bh * 64) * 2048;   // rows = dh, cols = n

    short8 qf[2][2];
    #pragma unroll
    for (int g = 0; g < 2; g++) {
        const int iw = i0 + wv * 32 + g * 16 + l16;
        qf[g][0] = *(const short8*)(qbase + (size_t)iw * 2048 + quad * 8);
        qf[g][1] = *(const short8*)(qbase + (size_t)iw * 2048 + 32 + quad * 8);
    }

    f32x4 O[2][4] = {};
    float l_lane[2] = {0.0f, 0.0f};

    const int sr = lane >> 3, ss = lane & 7;
    const int sck = ((ss - sr) & 7) * 8;
    const u16* kp0 = kbase + (size_t)(wv * 16 +      sr) * 2048 + sck;
    const u16* kp1 = kbase + (size_t)(wv * 16 + 8  + sr) * 2048 + sck;
    const u16* vp0 = vbase + (size_t)(wv * 16 +      sr) * 2048 + sck;
    const u16* vp1 = vbase + (size_t)(wv * 16 + 8  + sr) * 2048 + sck;

    const int swz0 = ((quad     + l16) & 7) * 8;
    const int swz1 = ((quad + 4 + l16) & 7) * 8;
    const u16* kb0 = &Ks[l16 * 64 + swz0];
    const u16* kb1 = &Ks[l16 * 64 + swz1];
    const u16* vb0 = &Vs[l16 * 64 + swz0];
    const u16* vb1 = &Vs[l16 * 64 + swz1];
    u16* pw = &Ps[(wv * 16 + l16) * 72];

    for (int j0 = 0; j0 < 2048; j0 += 64) {
        gload_lds16(kp0, &Ks[(wv * 16    ) * 64]);
        gload_lds16(kp1, &Ks[(wv * 16 + 8) * 64]);
        gload_lds16(vp0, &Vs[(wv * 16    ) * 64]);
        gload_lds16(vp1, &Vs[(wv * 16 + 8) * 64]);
        kp0 += 64 * 2048; kp1 += 64 * 2048; vp0 += 64; vp1 += 64;
        __syncthreads();

        f32x4 sfr[2][4];
        #pragma unroll
        for (int sub = 0; sub < 4; sub++) {
            short8 kf0 = *(const short8*)(kb0 + sub * 1024);
            short8 kf1 = *(const short8*)(kb1 + sub * 1024);
            f32x4 mrow = *(const f32x4*)&maskf[j0 + sub * 16 + quad * 4];
            #pragma unroll
            for (int g = 0; g < 2; g++) {
                f32x4 sz = mrow;
                sz = __builtin_amdgcn_mfma_f32_16x16x32_bf16(kf0, qf[g][0], sz, 0, 0, 0);
                sz = __builtin_amdgcn_mfma_f32_16x16x32_bf16(kf1, qf[g][1], sz, 0, 0, 0);
                sfr[g][sub] = sz;
            }
        }

        #pragma unroll
        for (int g = 0; g < 2; g++) {
            float lp = 0.0f;
            #pragma unroll
            for (int sub = 0; sub < 4; sub++)
                #pragma unroll
                for (int r = 0; r < 4; r++) {
                    float e = fast_exp2(sfr[g][sub][r]);
                    sfr[g][sub][r] = e;
                    lp += e;
                }
            l_lane[g] += lp;
            #pragma unroll
            for (int sub = 0; sub < 4; sub++) {
                u32x2 pk;
                pk.x = pack_trunc(sfr[g][sub][0], sfr[g][sub][1]);
                pk.y = pack_trunc(sfr[g][sub][2], sfr[g][sub][3]);
                *(u32x2*)(pw + g * 4608 + sub * 16 + quad * 4) = pk;
            }
        }

        short8 pf[2][2];
        #pragma unroll
        for (int g = 0; g < 2; g++) {
            pf[g][0] = *(const short8*)(pw + g * 4608 + quad * 8);
            pf[g][1] = *(const short8*)(pw + g * 4608 + 32 + quad * 8);
        }
        #pragma unroll
        for (int dht = 0; dht < 4; dht++) {
            short8 vf0 = *(const short8*)(vb0 + dht * 1024);
            short8 vf1 = *(const short8*)(vb1 + dht * 1024);
            #pragma unroll
            for (int g = 0; g < 2; g++) {
                O[g][dht] = __builtin_amdgcn_mfma_f32_16x16x32_bf16(vf0, pf[g][0], O[g][dht], 0, 0, 0);
                O[g][dht] = __builtin_amdgcn_mfma_f32_16x16x32_bf16(vf1, pf[g][1], O[g][dht], 0, 0, 0);
            }
        }
        __syncthreads();
    }

    #pragma unroll
    for (int g = 0; g < 2; g++) {
        float l = l_lane[g];
        l += __shfl_xor(l, 16, 64);
        l += __shfl_xor(l, 32, 64);
        const float inv = l > 0.0f ? 1.0f / l : 0.0f;
        const int iw = i0 + wv * 32 + g * 16 + l16;
        u16* cb = ctx + (size_t)(b * 2048 + iw) * 1024 + h * 64;
        #pragma unroll
        for (int dht = 0; dht < 4; dht++) {
            u32x2 pk;
            pk.x = (u32)f2bf(O[g][dht][0] * inv) | ((u32)f2bf(O[g][dht][1] * inv) << 16);
            pk.y = (u32)f2bf(O[g][dht][2] * inv) | ((u32)f2bf(O[g][dht][3] * inv) << 16);
            *(u32x2*)(cb + dht * 16 + quad * 4) = pk;
        }
    }
}

// ----------------------------------------------------------------
extern "C" void kernel_launch(void* const* d_in, const int* in_sizes, int n_in,
                              void* d_out, int out_size, void* d_ws, size_t ws_size,
                              hipStream_t stream)
{
    const int* mask = (const int*)d_in[1];

    u16* ws = (u16*)d_ws;
    u16* xn  = ws;                      // [0, 8388608)
    u16* qkb = ws + 8388608;            // [8388608, 25165824)  [8192][2048]
    u16* vtb = ws + 25165824;           // [25165824, 33554432) [4][16][64][2048]
    u16* ctx = xn;                      // xn dead after QKV GEMM; reuse
    u16* cW  = ws + 33554432;           // Wq|Wk|Wv|Wo
    u16* cV  = ws + 37748736;           // vectors (5376)
    int* mode = (int*)(ws + 37754176);

    detect_mode<<<dim3(1), dim3(256), 0, stream>>>((const u16*)d_in[0], mode);

    SrcPtrs sp;
    for (int i = 0; i < 13; i++) sp.p[i] = d_in[i + 2];
    convert_params<<<dim3(16405), dim3(256), 0, stream>>>(sp, ws, mode);

    ln_kernel<<<dim3(8192), dim3(256), 0, stream>>>(d_in[0], cV + 0, cV + 1024, xn, mode);

    // fused QKV + head-LN: N=3072, stacked W = cW (Wq|Wk|Wv), stacked bias = cV+2048
    gemm128<<<dim3(64, 24), dim3(256), 0, stream>>>(xn, cW, cV + 2048, qkb, vtb,
                                                    cV + 5120, cV + 5184, cV + 5248, cV + 5312,
                                                    mode, 1, 3072);

    attn<<<dim3(16, 64), dim3(256), 0, stream>>>(qkb, vtb, mask, ctx);

    gemm128<<<dim3(64, 8), dim3(256), 0, stream>>>(ctx, cW + 3145728, nullptr, d_out, nullptr,
                                                   nullptr, nullptr, nullptr, nullptr,
                                                   mode, 2, 1024);
}